// Round 7
// baseline (250.283 us; speedup 1.0000x reference)
//
#include <hip/hip_runtime.h>
#include <hip/hip_bf16.h>

#define HIDDEN 1152
#define NUM_HEADS 16
#define BATCH 8
#define SEQ 1024
#define MROWS (BATCH * SEQ)  // 8192
// log2(e) / sqrt(72): folded into Q so softmax can use exp2 directly
#define QSCALE_L2E (0.11785113019775793f * 1.4426950408889634f)

typedef __attribute__((ext_vector_type(8))) short short8;
typedef __attribute__((ext_vector_type(4))) float f32x4;

__device__ inline short f2bf(float x) {
  unsigned u = __float_as_uint(x);
  unsigned r = (u + 0x7FFFu + ((u >> 16) & 1u)) >> 16;
  return (short)(r & 0xFFFFu);
}

__device__ inline float fexp2(float x) { return __builtin_exp2f(x); }

__device__ inline void gload16(const void* g, void* l) {
  __builtin_amdgcn_global_load_lds(
      (const __attribute__((address_space(1))) void*)g,
      (__attribute__((address_space(3))) void*)l, 16, 0, 0);
}

// ---------------- x fp32 -> bf16 ----------------
__global__ __launch_bounds__(256) void k_cvtx(const float* __restrict__ X,
                                              short* __restrict__ Xb) {
  const size_t base = ((size_t)blockIdx.x * 256 + threadIdx.x) * 8;
  float4 a = *(const float4*)(X + base);
  float4 b = *(const float4*)(X + base + 4);
  short8 o = {f2bf(a.x), f2bf(a.y), f2bf(a.z), f2bf(a.w),
              f2bf(b.x), f2bf(b.y), f2bf(b.z), f2bf(b.w)};
  *(short8*)(Xb + base) = o;
}

// ---------------- W [K,N] fp32 -> Wt [N,K] bf16 (4 matrices) ----------------
__global__ __launch_bounds__(256) void k_cvtw(const float* __restrict__ W0,
                                              const float* __restrict__ W1,
                                              const float* __restrict__ W2,
                                              const float* __restrict__ W3,
                                              short* __restrict__ Wt) {
  __shared__ float T[64][65];
  const float* W = (blockIdx.z == 0) ? W0 : (blockIdx.z == 1) ? W1
                 : (blockIdx.z == 2) ? W2 : W3;
  short* dst = Wt + (size_t)blockIdx.z * HIDDEN * HIDDEN;
  const int n0 = blockIdx.x * 64, k0 = blockIdx.y * 64;
  const int tid = threadIdx.x;
  for (int t = tid; t < 4096; t += 256) {
    int r = t >> 6, c = t & 63;
    T[r][c] = W[(size_t)(k0 + r) * HIDDEN + n0 + c];
  }
  __syncthreads();
  for (int t = tid; t < 4096; t += 256) {
    int r = t >> 6, c = t & 63;
    dst[(size_t)(n0 + r) * HIDDEN + k0 + c] = f2bf(T[c][r]);
  }
}

// ---------------- zero Vt pad rows 72..79 ----------------
__global__ __launch_bounds__(256) void k_vzero(short* __restrict__ Vt) {
  const int t = blockIdx.x * 256 + threadIdx.x;  // 131072 threads
  const int bh = t >> 10;
  const int off = (t & 1023) * 8;
  const short8 z = {0, 0, 0, 0, 0, 0, 0, 0};
  *(short8*)(Vt + (size_t)bh * 81920 + 73728 + off) = z;
}

// ---------------- fused QKV GEMM: A[8192,1152] @ WtQKV[3456,1152]^T ----------
// Q: bf16 [bh][s][72] * QSCALE_L2E; K: bf16 [bh][s][72]; V: Vt[bh][80][1024]
__global__ __launch_bounds__(256) void k_gemm_qkv(
    const short* __restrict__ A, const short* __restrict__ Bt,
    const float* __restrict__ bq, const float* __restrict__ bk,
    const float* __restrict__ bv, short* __restrict__ Qb,
    short* __restrict__ Kb, short* __restrict__ Vt) {
  __shared__ __align__(16) short SM[16384];  // As | Bs; reused as Td in V-epilogue
  short* As = SM;
  short* Bs = SM + 8192;
  const int tid = threadIdx.x;
  const int lane = tid & 63;
  const int wid = tid >> 6;
  const int wr = wid >> 1, wc = wid & 1;
  // XCD-chunked bijective swizzle over 1728 blocks
  const int flat = blockIdx.y * 27 + blockIdx.x;
  const int rid = (flat & 7) * 216 + (flat >> 3);
  const int row0 = (rid / 27) << 7;
  const int col0 = (rid % 27) << 7;
  const int l15 = lane & 15, lh = lane >> 4;
  const int lr8 = lane >> 3;
  const int csrc = ((lane & 7) ^ lr8) << 3;

  const f32x4 fz = {0.f, 0.f, 0.f, 0.f};
  f32x4 acc[4][4];
#pragma unroll
  for (int m = 0; m < 4; ++m)
#pragma unroll
    for (int n = 0; n < 4; ++n) acc[m][n] = fz;

  for (int k0 = 0; k0 < HIDDEN; k0 += 64) {
#pragma unroll
    for (int i = 0; i < 4; ++i) {
      const int chunk = (wid << 2) + i;
      const int r = (chunk << 3) + lr8;
      gload16(A + (size_t)(row0 + r) * HIDDEN + k0 + csrc, (void*)(As + (chunk << 9)));
      gload16(Bt + (size_t)(col0 + r) * HIDDEN + k0 + csrc, (void*)(Bs + (chunk << 9)));
    }
    __syncthreads();
#pragma unroll
    for (int ks = 0; ks < 2; ++ks) {
      short8 af[4], bfr[4];
#pragma unroll
      for (int m = 0; m < 4; ++m) {
        const int r = (wr << 6) + (m << 4) + l15;
        const int off = ((ks << 6) + (lh << 4)) ^ ((r & 7) << 4);
        af[m] = *(const short8*)((const char*)As + r * 128 + off);
      }
#pragma unroll
      for (int n = 0; n < 4; ++n) {
        const int r = (wc << 6) + (n << 4) + l15;
        const int off = ((ks << 6) + (lh << 4)) ^ ((r & 7) << 4);
        bfr[n] = *(const short8*)((const char*)Bs + r * 128 + off);
      }
      __builtin_amdgcn_s_setprio(1);
#pragma unroll
      for (int m = 0; m < 4; ++m)
#pragma unroll
        for (int n = 0; n < 4; ++n)
          acc[m][n] = __builtin_amdgcn_mfma_f32_16x16x32_bf16(af[m], bfr[n], acc[m][n], 0, 0, 0);
      __builtin_amdgcn_s_setprio(0);
    }
    __syncthreads();
  }

  const int cseg = (rid % 27) / 9;  // 0=Q 1=K 2=V (wave-uniform)
  if (cseg < 2) {
    short* dst = (cseg == 0) ? Qb : Kb;
    const float* bias = (cseg == 0) ? bq : bk;
    const float scl = (cseg == 0) ? QSCALE_L2E : 1.0f;
#pragma unroll
    for (int n = 0; n < 4; ++n) {
      const int c = col0 - cseg * HIDDEN + (wc << 6) + (n << 4) + l15;
      const int h = c / 72;
      const int d = c - h * 72;
      const float bvx = bias[c];
#pragma unroll
      for (int m = 0; m < 4; ++m)
#pragma unroll
        for (int i = 0; i < 4; ++i) {
          const int r = row0 + (wr << 6) + (m << 4) + (lh << 2) + i;
          const int b = r >> 10, s = r & 1023;
          dst[(size_t)((((b << 4) + h) << 10) + s) * 72 + d] =
              f2bf((acc[m][n][i] + bvx) * scl);
        }
    }
  } else {
    // ---- V segment: LDS transpose -> coalesced [d][s] stores ----
    const int cbase = col0 - 2 * HIDDEN;
    const int b = row0 >> 10;
    const int sb = row0 & 1023;
    short* Td = SM;  // 64 x 136 shorts (17 KB of the 32 KB SM)
#pragma unroll
    for (int p = 0; p < 2; ++p) {
      if (wc == p) {
#pragma unroll
        for (int n = 0; n < 4; ++n) {
          const int ci = n * 16 + l15;  // 0..63 within pass
          const float bvx = bv[cbase + p * 64 + ci];
#pragma unroll
          for (int m = 0; m < 4; ++m) {
            const int r0 = (wr << 6) + (m << 4) + (lh << 2);
            short4 o;
            o.x = f2bf(acc[m][n][0] + bvx);
            o.y = f2bf(acc[m][n][1] + bvx);
            o.z = f2bf(acc[m][n][2] + bvx);
            o.w = f2bf(acc[m][n][3] + bvx);
            *(short4*)(Td + ci * 136 + r0) = o;
          }
        }
      }
      __syncthreads();
      {
        const int row = tid >> 2;   // 0..63
        const int part = tid & 3;   // 0..3
        const int cg = cbase + p * 64 + row;
        const int h = cg / 72;
        const int d = cg - h * 72;
        short* dstp = Vt + (((size_t)(((b << 4) + h) * 80 + d)) << 10) + sb + part * 32;
        const short* srcp = Td + row * 136 + part * 32;
#pragma unroll
        for (int k = 0; k < 4; ++k)
          *(short8*)(dstp + k * 8) = *(const short8*)(srcp + k * 8);
      }
      __syncthreads();
    }
  }
}

// ---------------- O GEMM: C fp32 = A[8192,1152]bf16 @ Wt[N,K]^T + bias -------
__global__ __launch_bounds__(256) void k_gemm_o(const short* __restrict__ A,
                                                const short* __restrict__ Bt,
                                                const float* __restrict__ bias,
                                                float* __restrict__ C) {
  __shared__ __align__(16) short As[8192];
  __shared__ __align__(16) short Bs[8192];
  const int tid = threadIdx.x;
  const int lane = tid & 63;
  const int wid = tid >> 6;
  const int wr = wid >> 1, wc = wid & 1;
  const int flat = blockIdx.y * 9 + blockIdx.x;
  const int rid = (flat & 7) * 72 + (flat >> 3);
  const int row0 = (rid / 9) << 7;
  const int col0 = (rid % 9) << 7;
  const int l15 = lane & 15, lh = lane >> 4;
  const int lr8 = lane >> 3;
  const int csrc = ((lane & 7) ^ lr8) << 3;

  const f32x4 fz = {0.f, 0.f, 0.f, 0.f};
  f32x4 acc[4][4];
#pragma unroll
  for (int m = 0; m < 4; ++m)
#pragma unroll
    for (int n = 0; n < 4; ++n) acc[m][n] = fz;

  for (int k0 = 0; k0 < HIDDEN; k0 += 64) {
#pragma unroll
    for (int i = 0; i < 4; ++i) {
      const int chunk = (wid << 2) + i;
      const int r = (chunk << 3) + lr8;
      gload16(A + (size_t)(row0 + r) * HIDDEN + k0 + csrc, (void*)(As + (chunk << 9)));
      gload16(Bt + (size_t)(col0 + r) * HIDDEN + k0 + csrc, (void*)(Bs + (chunk << 9)));
    }
    __syncthreads();
#pragma unroll
    for (int ks = 0; ks < 2; ++ks) {
      short8 af[4], bfr[4];
#pragma unroll
      for (int m = 0; m < 4; ++m) {
        const int r = (wr << 6) + (m << 4) + l15;
        const int off = ((ks << 6) + (lh << 4)) ^ ((r & 7) << 4);
        af[m] = *(const short8*)((const char*)As + r * 128 + off);
      }
#pragma unroll
      for (int n = 0; n < 4; ++n) {
        const int r = (wc << 6) + (n << 4) + l15;
        const int off = ((ks << 6) + (lh << 4)) ^ ((r & 7) << 4);
        bfr[n] = *(const short8*)((const char*)Bs + r * 128 + off);
      }
      __builtin_amdgcn_s_setprio(1);
#pragma unroll
      for (int m = 0; m < 4; ++m)
#pragma unroll
        for (int n = 0; n < 4; ++n)
          acc[m][n] = __builtin_amdgcn_mfma_f32_16x16x32_bf16(af[m], bfr[n], acc[m][n], 0, 0, 0);
      __builtin_amdgcn_s_setprio(0);
    }
    __syncthreads();
  }

#pragma unroll
  for (int n = 0; n < 4; ++n) {
    const int c = col0 + (wc << 6) + (n << 4) + l15;
    const float bvx = bias[c];
#pragma unroll
    for (int m = 0; m < 4; ++m)
#pragma unroll
      for (int i = 0; i < 4; ++i) {
        const int r = row0 + (wr << 6) + (m << 4) + (lh << 2) + i;
        C[(size_t)r * HIDDEN + c] = acc[m][n][i] + bvx;
      }
  }
}

// ---------------- attention helpers ----------------
__device__ __forceinline__ void stage_kv(const char* kgb, const char* vgb, int t,
                                         short* ks, short* vs, int wid, int lane) {
  const char* kg = kgb + (size_t)t * 9216;  // K tile [64][72] bf16, contiguous
  for (int c = wid; c < 9; c += 4)
    gload16(kg + c * 1024 + lane * 16, (char*)ks + c * 1024);
  for (int c = wid; c < 10; c += 4) {
    const int p = c * 1024 + lane * 16;
    const int d = p >> 7;                    // 0..79
    const int sc16 = (lane & 7) ^ (d & 7);   // pre-swizzled source chunk
    gload16(vgb + (size_t)d * 2048 + t * 128 + sc16 * 16, (char*)vs + c * 1024);
  }
}

__device__ __forceinline__ void attn_tile(
    const short* Ks, const short* Vs, short* psw, const short8 (&qf)[2][3],
    float (&mrun)[2], float (&lrun)[2], f32x4 (&oacc)[2][5], int l15, int lh) {
  const f32x4 fz = {0.f, 0.f, 0.f, 0.f};
#pragma unroll
  for (int m = 0; m < 2; ++m) {
    // ---- QK^T swapped: lane holds 16 consecutive keys of q-row l15 ----
    f32x4 sa[4];
#pragma unroll
    for (int n = 0; n < 4; ++n) sa[n] = fz;
#pragma unroll
    for (int ks = 0; ks < 3; ++ks) {
      short8 kf[4];
#pragma unroll
      for (int n = 0; n < 4; ++n) {
        const char* krow = (const char*)Ks + (n * 16 + l15) * 144;
        if (ks < 2)
          kf[n] = *(const short8*)(krow + ks * 64 + lh * 16);
        else
          kf[n] = *(const short8*)(krow + 128);  // broadcast; d>=72 garbage * Q-zero
      }
      __builtin_amdgcn_s_setprio(1);
#pragma unroll
      for (int n = 0; n < 4; ++n)
        sa[n] = __builtin_amdgcn_mfma_f32_16x16x32_bf16(kf[n], qf[m][ks], sa[n], 0, 0, 0);
      __builtin_amdgcn_s_setprio(0);
    }

    // ---- online softmax, log2 domain (row = q = l15; reduce over lh) ----
    float mx = sa[0][0];
#pragma unroll
    for (int n = 0; n < 4; ++n)
#pragma unroll
      for (int i = 0; i < 4; ++i) mx = fmaxf(mx, sa[n][i]);
    mx = fmaxf(mx, __shfl_xor(mx, 16));
    mx = fmaxf(mx, __shfl_xor(mx, 32));

    const bool skip = __all(mx <= mrun[m] + 8.0f);
    if (!skip) {
      const float nm = fmaxf(mrun[m], mx);
      const float corr = fexp2(mrun[m] - nm);
      lrun[m] *= corr;
      mrun[m] = nm;
      float c0 = __shfl(corr, lh * 4 + 0);
      float c1 = __shfl(corr, lh * 4 + 1);
      float c2 = __shfl(corr, lh * 4 + 2);
      float c3 = __shfl(corr, lh * 4 + 3);
      const f32x4 cv = {c0, c1, c2, c3};
#pragma unroll
      for (int no = 0; no < 5; ++no) oacc[m][no] *= cv;
    }

    float ps = 0.f;
#pragma unroll
    for (int n = 0; n < 4; ++n)
#pragma unroll
      for (int i = 0; i < 4; ++i) {
        const float p = fexp2(sa[n][i] - mrun[m]);
        sa[n][i] = p;
        ps += p;
      }
    ps += __shfl_xor(ps, 16);
    ps += __shfl_xor(ps, 32);
    lrun[m] += ps;

    // ---- P -> per-wave LDS (bf16 pack via v_perm, ds_write_b64) ----
#pragma unroll
    for (int n = 0; n < 4; ++n) {
      unsigned w0 = __builtin_amdgcn_perm(__float_as_uint(sa[n][1]),
                                          __float_as_uint(sa[n][0]), 0x07060302u);
      unsigned w1 = __builtin_amdgcn_perm(__float_as_uint(sa[n][3]),
                                          __float_as_uint(sa[n][2]), 0x07060302u);
      uint2 w = {w0, w1};
      *(uint2*)((char*)psw + l15 * 144 + n * 32 + lh * 8) = w;
    }

    // ---- PV ----
#pragma unroll
    for (int ks = 0; ks < 2; ++ks) {
      const short8 pa = *(const short8*)((const char*)psw + l15 * 144 + ks * 64 + lh * 16);
      short8 vb[5];
      const int cc = ((ks << 2) + lh) ^ (l15 & 7);
#pragma unroll
      for (int no = 0; no < 5; ++no)
        vb[no] = *(const short8*)((const char*)Vs + no * 2048 + l15 * 128 + cc * 16);
      __builtin_amdgcn_s_setprio(1);
#pragma unroll
      for (int no = 0; no < 5; ++no)
        oacc[m][no] = __builtin_amdgcn_mfma_f32_16x16x32_bf16(pa, vb[no], oacc[m][no], 0, 0, 0);
      __builtin_amdgcn_s_setprio(0);
    }
  }
}

// ---------------- Flash attention (2-phase double-buffered staging) ----------
// grid: 1024 blocks (XCD-chunked -> (qtile, bh)). 4 waves x 32 q-rows. KB=64.
__global__ __launch_bounds__(256, 4) void k_attn(const short* __restrict__ Qg,
                                                 const short* __restrict__ Kg,
                                                 const short* __restrict__ Vt,
                                                 short* __restrict__ Og) {
  __shared__ __align__(16) short Ks0[64 * 72], Ks1[64 * 72];  // 9216 B each
  __shared__ __align__(16) short Vs0[80 * 64], Vs1[80 * 64];  // 10240 B each
  __shared__ __align__(16) short Ps[4 * 16 * 72];             // 9216 B
  const int tid = threadIdx.x, lane = tid & 63, wid = tid >> 6;
  const int l15 = lane & 15, lh = lane >> 4;
  const int id = blockIdx.x;
  const int rid = (id & 7) * 128 + (id >> 3);
  const int bh = rid >> 3;
  const int q0 = (rid & 7) << 7;
  const short8 sz = {0, 0, 0, 0, 0, 0, 0, 0};
  const f32x4 fz = {0.f, 0.f, 0.f, 0.f};

  // Q fragments in registers (pre-scaled by log2e/sqrt(72) in the QKV GEMM)
  short8 qf[2][3];
#pragma unroll
  for (int m = 0; m < 2; ++m)
#pragma unroll
    for (int ks = 0; ks < 3; ++ks) {
      const int row = q0 + wid * 32 + m * 16 + l15;
      const int e0 = ks * 32 + lh * 8;
      if (e0 < 72)
        qf[m][ks] = *(const short8*)(Qg + ((size_t)bh * 1024 + row) * 72 + e0);
      else
        qf[m][ks] = sz;
    }

  float mrun[2] = {-1e30f, -1e30f};
  float lrun[2] = {0.f, 0.f};
  f32x4 oacc[2][5];
#pragma unroll
  for (int m = 0; m < 2; ++m)
#pragma unroll
    for (int no = 0; no < 5; ++no) oacc[m][no] = fz;

  const char* kgb = (const char*)Kg + (size_t)bh * 147456;  // 1024*72*2
  const char* vgb = (const char*)Vt + (size_t)bh * 163840;
  short* psw = Ps + wid * 1152;

  stage_kv(kgb, vgb, 0, Ks0, Vs0, wid, lane);
  __syncthreads();

  for (int t = 0; t < 16; t += 2) {
    if (t + 1 < 16) stage_kv(kgb, vgb, t + 1, Ks1, Vs1, wid, lane);
    attn_tile(Ks0, Vs0, psw, qf, mrun, lrun, oacc, l15, lh);
    __syncthreads();
    if (t + 2 < 16) stage_kv(kgb, vgb, t + 2, Ks0, Vs0, wid, lane);
    attn_tile(Ks1, Vs1, psw, qf, mrun, lrun, oacc, l15, lh);
    __syncthreads();
  }

  // ---- epilogue ----
  const int b = bh >> 4, h = bh & 15;
#pragma unroll
  for (int m = 0; m < 2; ++m) {
    const float il = 1.0f / lrun[m];
    float inv[4];
#pragma unroll
    for (int i = 0; i < 4; ++i) inv[i] = __shfl(il, lh * 4 + i);
#pragma unroll
    for (int no = 0; no < 5; ++no) {
      const int d = no * 16 + l15;
      if (d < 72) {
#pragma unroll
        for (int i = 0; i < 4; ++i) {
          const int s = q0 + wid * 32 + m * 16 + lh * 4 + i;
          Og[((size_t)(b * 1024 + s)) * HIDDEN + h * 72 + d] = f2bf(oacc[m][no][i] * inv[i]);
        }
      }
    }
  }
}

// ---------------- launch ----------------
extern "C" void kernel_launch(void* const* d_in, const int* in_sizes, int n_in,
                              void* d_out, int out_size, void* d_ws, size_t ws_size,
                              hipStream_t stream) {
  const float* x  = (const float*)d_in[0];
  const float* wq = (const float*)d_in[1];
  const float* bq = (const float*)d_in[2];
  const float* wk = (const float*)d_in[3];
  const float* bk = (const float*)d_in[4];
  const float* wv = (const float*)d_in[5];
  const float* bv = (const float*)d_in[6];
  const float* wo = (const float*)d_in[7];
  const float* bo = (const float*)d_in[8];

  char* ws = (char*)d_ws;
  short* xb = (short*)ws;                    // 18,874,368 B (bf16 x; reused as attn out)
  short* wT = (short*)(ws + 18874368);       // 10,616,832 B
  short* Qb = (short*)(ws + 29491200);       // 18,874,368 B [bh][s][72]
  short* Kb = (short*)(ws + 48365568);       // 18,874,368 B [bh][s][72]
  short* Vt = (short*)(ws + 67239936);       // 20,971,520 B [bh][80][1024]
  const size_t WSZ = (size_t)HIDDEN * HIDDEN;

  k_cvtx<<<4608, 256, 0, stream>>>(x, xb);
  k_cvtw<<<dim3(18, 18, 4), 256, 0, stream>>>(wq, wk, wv, wo, wT);
  k_vzero<<<512, 256, 0, stream>>>(Vt);

  k_gemm_qkv<<<dim3(27, 64), 256, 0, stream>>>(xb, wT, bq, bk, bv, Qb, Kb, Vt);
  k_attn<<<1024, 256, 0, stream>>>(Qb, Kb, Vt, xb);
  k_gemm_o<<<dim3(9, 64), 256, 0, stream>>>(xb, wT + 3 * WSZ, bo, (float*)d_out);
}

// Round 8
// 227.959 us; speedup vs baseline: 1.0979x; 1.0979x over previous
//
#include <hip/hip_runtime.h>
#include <hip/hip_bf16.h>

#define HIDDEN 1152
#define NUM_HEADS 16
#define BATCH 8
#define SEQ 1024
#define MROWS (BATCH * SEQ)  // 8192
#define KSTRIDE 104          // padded K row length (shorts)
// log2(e) / sqrt(72): folded into Q so softmax can use exp2 directly
#define QSCALE_L2E (0.11785113019775793f * 1.4426950408889634f)

typedef __attribute__((ext_vector_type(8))) short short8;
typedef __attribute__((ext_vector_type(4))) float f32x4;

__device__ inline short f2bf(float x) {
  unsigned u = __float_as_uint(x);
  unsigned r = (u + 0x7FFFu + ((u >> 16) & 1u)) >> 16;
  return (short)(r & 0xFFFFu);
}

__device__ inline float fexp2(float x) { return __builtin_exp2f(x); }

__device__ inline void gload16(const void* g, void* l) {
  __builtin_amdgcn_global_load_lds(
      (const __attribute__((address_space(1))) void*)g,
      (__attribute__((address_space(3))) void*)l, 16, 0, 0);
}

// ---------------- x fp32 -> bf16 ----------------
__global__ __launch_bounds__(256) void k_cvtx(const float* __restrict__ X,
                                              short* __restrict__ Xb) {
  const size_t base = ((size_t)blockIdx.x * 256 + threadIdx.x) * 8;
  float4 a = *(const float4*)(X + base);
  float4 b = *(const float4*)(X + base + 4);
  short8 o = {f2bf(a.x), f2bf(a.y), f2bf(a.z), f2bf(a.w),
              f2bf(b.x), f2bf(b.y), f2bf(b.z), f2bf(b.w)};
  *(short8*)(Xb + base) = o;
}

// ---------------- W [K,N] fp32 -> Wt [N,K] bf16 (4 matrices) ----------------
__global__ __launch_bounds__(256) void k_cvtw(const float* __restrict__ W0,
                                              const float* __restrict__ W1,
                                              const float* __restrict__ W2,
                                              const float* __restrict__ W3,
                                              short* __restrict__ Wt) {
  __shared__ float T[64][65];
  const float* W = (blockIdx.z == 0) ? W0 : (blockIdx.z == 1) ? W1
                 : (blockIdx.z == 2) ? W2 : W3;
  short* dst = Wt + (size_t)blockIdx.z * HIDDEN * HIDDEN;
  const int n0 = blockIdx.x * 64, k0 = blockIdx.y * 64;
  const int tid = threadIdx.x;
  for (int t = tid; t < 4096; t += 256) {
    int r = t >> 6, c = t & 63;
    T[r][c] = W[(size_t)(k0 + r) * HIDDEN + n0 + c];
  }
  __syncthreads();
  for (int t = tid; t < 4096; t += 256) {
    int r = t >> 6, c = t & 63;
    dst[(size_t)(n0 + r) * HIDDEN + k0 + c] = f2bf(T[c][r]);
  }
}

// ---------------- zero K pad columns 72..95 ----------------
__global__ __launch_bounds__(256) void k_kpad(short* __restrict__ Kp) {
  const int r = blockIdx.x * 256 + threadIdx.x;  // 131072 rows
  const short8 z = {0, 0, 0, 0, 0, 0, 0, 0};
  short* p = Kp + (size_t)r * KSTRIDE + 72;
  *(short8*)(p) = z;
  *(short8*)(p + 8) = z;
  *(short8*)(p + 16) = z;
}

// ---------------- zero Vt pad rows 72..79 ----------------
__global__ __launch_bounds__(256) void k_vzero(short* __restrict__ Vt) {
  const int t = blockIdx.x * 256 + threadIdx.x;  // 131072 threads
  const int bh = t >> 10;
  const int off = (t & 1023) * 8;
  const short8 z = {0, 0, 0, 0, 0, 0, 0, 0};
  *(short8*)(Vt + (size_t)bh * 81920 + 73728 + off) = z;
}

// ---------------- fused QKV GEMM: 256x128 tile, 512 threads (8 waves) --------
// Q: bf16 [bh][s][72] * QSCALE_L2E; K: bf16 [bh][s][104] padded; V: Vt[bh][80][1024]
__global__ __launch_bounds__(512) void k_gemm_qkv(
    const short* __restrict__ A, const short* __restrict__ Bt,
    const float* __restrict__ bq, const float* __restrict__ bk,
    const float* __restrict__ bv, short* __restrict__ Qb,
    short* __restrict__ Kp, short* __restrict__ Vt) {
  __shared__ __align__(16) short SM[24576];  // As(32KB) | Bs(16KB); Td in V-epilogue
  short* As = SM;          // [256][64] bf16, XOR-swizzled
  short* Bs = SM + 16384;  // [128][64]
  const int tid = threadIdx.x;
  const int lane = tid & 63;
  const int wid = tid >> 6;        // 0..7
  const int wr = wid >> 1, wc = wid & 1;
  // XCD-chunked bijective swizzle over 864 blocks (864 = 8*108)
  const int flat = blockIdx.y * 27 + blockIdx.x;
  const int rid = (flat & 7) * 108 + (flat >> 3);
  const int row0 = (rid / 27) << 8;      // 0..7936, step 256
  const int colTile = rid % 27;
  const int col0 = colTile << 7;
  const int l15 = lane & 15, lh = lane >> 4;
  const int lr8 = lane >> 3;
  const int csrc = ((lane & 7) ^ lr8) << 3;  // pre-swizzled source col (shorts)

  const f32x4 fz = {0.f, 0.f, 0.f, 0.f};
  f32x4 acc[4][4];
#pragma unroll
  for (int m = 0; m < 4; ++m)
#pragma unroll
    for (int n = 0; n < 4; ++n) acc[m][n] = fz;

  for (int k0 = 0; k0 < HIDDEN; k0 += 64) {
#pragma unroll
    for (int i = 0; i < 4; ++i) {  // A: 32 chunks of 1KB
      const int c = (wid << 2) + i;
      const int r = (c << 3) + lr8;
      gload16(A + (size_t)(row0 + r) * HIDDEN + k0 + csrc, (void*)(As + (c << 9)));
    }
#pragma unroll
    for (int i = 0; i < 2; ++i) {  // B: 16 chunks of 1KB
      const int c = (wid << 1) + i;
      const int r = (c << 3) + lr8;
      gload16(Bt + (size_t)(col0 + r) * HIDDEN + k0 + csrc, (void*)(Bs + (c << 9)));
    }
    __syncthreads();
#pragma unroll
    for (int ks = 0; ks < 2; ++ks) {
      short8 af[4], bfr[4];
#pragma unroll
      for (int m = 0; m < 4; ++m) {
        const int r = (wr << 6) + (m << 4) + l15;
        const int off = ((ks << 6) + (lh << 4)) ^ ((r & 7) << 4);
        af[m] = *(const short8*)((const char*)As + r * 128 + off);
      }
#pragma unroll
      for (int n = 0; n < 4; ++n) {
        const int r = (wc << 6) + (n << 4) + l15;
        const int off = ((ks << 6) + (lh << 4)) ^ ((r & 7) << 4);
        bfr[n] = *(const short8*)((const char*)Bs + r * 128 + off);
      }
      __builtin_amdgcn_s_setprio(1);
#pragma unroll
      for (int m = 0; m < 4; ++m)
#pragma unroll
        for (int n = 0; n < 4; ++n)
          acc[m][n] = __builtin_amdgcn_mfma_f32_16x16x32_bf16(af[m], bfr[n], acc[m][n], 0, 0, 0);
      __builtin_amdgcn_s_setprio(0);
    }
    __syncthreads();
  }

  const int cseg = colTile / 9;          // 0=Q 1=K 2=V (block-uniform)
  const int cwithin = (colTile % 9) << 7;  // col base within segment
  if (cseg < 2) {
    short* dst = (cseg == 0) ? Qb : Kp;
    const float* bias = (cseg == 0) ? bq : bk;
    const float scl = (cseg == 0) ? QSCALE_L2E : 1.0f;
    const int rstride = (cseg == 0) ? 72 : KSTRIDE;
#pragma unroll
    for (int n = 0; n < 4; ++n) {
      const int c = cwithin + (wc << 6) + (n << 4) + l15;
      const int h = c / 72;
      const int d = c - h * 72;
      const float bvx = bias[c];
#pragma unroll
      for (int m = 0; m < 4; ++m)
#pragma unroll
        for (int i = 0; i < 4; ++i) {
          const int r = row0 + (wr << 6) + (m << 4) + (lh << 2) + i;
          const int b = r >> 10, s = r & 1023;
          dst[(size_t)((((b << 4) + h) << 10) + s) * rstride + d] =
              f2bf((acc[m][n][i] + bvx) * scl);
        }
    }
  } else {
    // ---- V segment: LDS transpose -> coalesced [d][s] stores ----
    const int b = row0 >> 10;
    const int sb = row0 & 1023;
    short* Td = SM;  // 64 cols x 264 (rows 0..255 + pad)
#pragma unroll
    for (int p = 0; p < 2; ++p) {
      if (wc == p) {
#pragma unroll
        for (int n = 0; n < 4; ++n) {
          const int ci = n * 16 + l15;  // 0..63 within pass
          const float bvx = bv[cwithin + p * 64 + ci];
#pragma unroll
          for (int m = 0; m < 4; ++m) {
            const int r0 = (wr << 6) + (m << 4) + (lh << 2);
            short4 o;
            o.x = f2bf(acc[m][n][0] + bvx);
            o.y = f2bf(acc[m][n][1] + bvx);
            o.z = f2bf(acc[m][n][2] + bvx);
            o.w = f2bf(acc[m][n][3] + bvx);
            *(short4*)(Td + ci * 264 + r0) = o;
          }
        }
      }
      __syncthreads();
      {
        const int ci = tid >> 3;    // 0..63
        const int part = tid & 7;   // 0..7, 32 shorts each
        const int cg = cwithin + p * 64 + ci;
        const int h = cg / 72;
        const int d = cg - h * 72;
        short* dstp = Vt + (((size_t)(((b << 4) + h) * 80 + d)) << 10) + sb + part * 32;
        const short* srcp = Td + ci * 264 + part * 32;
#pragma unroll
        for (int k = 0; k < 4; ++k)
          *(short8*)(dstp + k * 8) = *(const short8*)(srcp + k * 8);
      }
      __syncthreads();
    }
  }
}

// ---------------- O GEMM: C fp32 = A[8192,1152]bf16 @ Wt[N,K]^T + bias -------
__global__ __launch_bounds__(256) void k_gemm_o(const short* __restrict__ A,
                                                const short* __restrict__ Bt,
                                                const float* __restrict__ bias,
                                                float* __restrict__ C) {
  __shared__ __align__(16) short As[8192];
  __shared__ __align__(16) short Bs[8192];
  const int tid = threadIdx.x;
  const int lane = tid & 63;
  const int wid = tid >> 6;
  const int wr = wid >> 1, wc = wid & 1;
  const int flat = blockIdx.y * 9 + blockIdx.x;
  const int rid = (flat & 7) * 72 + (flat >> 3);
  const int row0 = (rid / 9) << 7;
  const int col0 = (rid % 9) << 7;
  const int l15 = lane & 15, lh = lane >> 4;
  const int lr8 = lane >> 3;
  const int csrc = ((lane & 7) ^ lr8) << 3;

  const f32x4 fz = {0.f, 0.f, 0.f, 0.f};
  f32x4 acc[4][4];
#pragma unroll
  for (int m = 0; m < 4; ++m)
#pragma unroll
    for (int n = 0; n < 4; ++n) acc[m][n] = fz;

  for (int k0 = 0; k0 < HIDDEN; k0 += 64) {
#pragma unroll
    for (int i = 0; i < 4; ++i) {
      const int chunk = (wid << 2) + i;
      const int r = (chunk << 3) + lr8;
      gload16(A + (size_t)(row0 + r) * HIDDEN + k0 + csrc, (void*)(As + (chunk << 9)));
      gload16(Bt + (size_t)(col0 + r) * HIDDEN + k0 + csrc, (void*)(Bs + (chunk << 9)));
    }
    __syncthreads();
#pragma unroll
    for (int ks = 0; ks < 2; ++ks) {
      short8 af[4], bfr[4];
#pragma unroll
      for (int m = 0; m < 4; ++m) {
        const int r = (wr << 6) + (m << 4) + l15;
        const int off = ((ks << 6) + (lh << 4)) ^ ((r & 7) << 4);
        af[m] = *(const short8*)((const char*)As + r * 128 + off);
      }
#pragma unroll
      for (int n = 0; n < 4; ++n) {
        const int r = (wc << 6) + (n << 4) + l15;
        const int off = ((ks << 6) + (lh << 4)) ^ ((r & 7) << 4);
        bfr[n] = *(const short8*)((const char*)Bs + r * 128 + off);
      }
      __builtin_amdgcn_s_setprio(1);
#pragma unroll
      for (int m = 0; m < 4; ++m)
#pragma unroll
        for (int n = 0; n < 4; ++n)
          acc[m][n] = __builtin_amdgcn_mfma_f32_16x16x32_bf16(af[m], bfr[n], acc[m][n], 0, 0, 0);
      __builtin_amdgcn_s_setprio(0);
    }
    __syncthreads();
  }

#pragma unroll
  for (int n = 0; n < 4; ++n) {
    const int c = col0 + (wc << 6) + (n << 4) + l15;
    const float bvx = bias[c];
#pragma unroll
    for (int m = 0; m < 4; ++m)
#pragma unroll
      for (int i = 0; i < 4; ++i) {
        const int r = row0 + (wr << 6) + (m << 4) + (lh << 2) + i;
        C[(size_t)r * HIDDEN + c] = acc[m][n][i] + bvx;
      }
  }
}

// ---------------- Flash attention (R6 proven structure) ----------------
// grid: 1024 blocks (XCD-chunked -> (qtile, bh)). 4 waves x 32 q-rows. KB=64.
__global__ __launch_bounds__(256, 4) void k_attn(const short* __restrict__ Qg,
                                                 const short* __restrict__ Kp,
                                                 const short* __restrict__ Vt,
                                                 short* __restrict__ Og) {
  __shared__ __align__(16) short Ks[64 * KSTRIDE];  // 13312 B, linear
  __shared__ __align__(16) short Vs[80 * 64];       // 10240 B, XOR-swizzled content
  __shared__ __align__(16) short Ps[4 * 16 * 72];   // 9216 B, per-wave 16 q-rows
  const int tid = threadIdx.x, lane = tid & 63, wid = tid >> 6;
  const int l15 = lane & 15, lh = lane >> 4;
  const int id = blockIdx.x;
  const int rid = (id & 7) * 128 + (id >> 3);
  const int bh = rid >> 3;
  const int q0 = (rid & 7) << 7;
  const short8 sz = {0, 0, 0, 0, 0, 0, 0, 0};
  const f32x4 fz = {0.f, 0.f, 0.f, 0.f};

  // Q fragments in registers (pre-scaled by log2e/sqrt(72) in the QKV GEMM)
  short8 qf[2][3];
#pragma unroll
  for (int m = 0; m < 2; ++m)
#pragma unroll
    for (int ks = 0; ks < 3; ++ks) {
      const int row = q0 + wid * 32 + m * 16 + l15;
      const int e0 = ks * 32 + lh * 8;
      if (e0 < 72)
        qf[m][ks] = *(const short8*)(Qg + ((size_t)bh * 1024 + row) * 72 + e0);
      else
        qf[m][ks] = sz;
    }

  float mrun[2] = {-1e30f, -1e30f};
  float lrun[2] = {0.f, 0.f};
  f32x4 oacc[2][5];
#pragma unroll
  for (int m = 0; m < 2; ++m)
#pragma unroll
    for (int no = 0; no < 5; ++no) oacc[m][no] = fz;

  const char* kgb = (const char*)Kp + ((size_t)bh * 1024) * (KSTRIDE * 2);
  const char* vgb = (const char*)Vt + (size_t)bh * 163840;

  for (int kt = 0; kt < 16; ++kt) {
    // ---- stage K tile: 13 contiguous 1KB wave-chunks ----
    const char* kg = kgb + (size_t)kt * 64 * (KSTRIDE * 2);
    for (int c = wid; c < 13; c += 4)
      gload16(kg + c * 1024 + lane * 16, (char*)Ks + c * 1024);
    // ---- stage V tile: linear LDS, pre-swizzled global source ----
    for (int c = wid; c < 10; c += 4) {
      const int p = c * 1024 + lane * 16;
      const int d = p >> 7;                       // 0..79
      const int sc16 = (lane & 7) ^ (d & 7);      // swizzled source chunk
      gload16(vgb + (size_t)d * 2048 + kt * 128 + sc16 * 16, (char*)Vs + c * 1024);
    }
    __syncthreads();

#pragma unroll
    for (int m = 0; m < 2; ++m) {
      // ---- QK^T swapped: lane holds 16 consecutive keys of q-row l15 ----
      f32x4 sa[4];
#pragma unroll
      for (int n = 0; n < 4; ++n) sa[n] = fz;
#pragma unroll
      for (int ks = 0; ks < 3; ++ks) {
        short8 kf[4];
#pragma unroll
        for (int n = 0; n < 4; ++n)
          kf[n] = *(const short8*)((const char*)Ks + (n * 16 + l15) * 208 + ks * 64 + lh * 16);
        __builtin_amdgcn_s_setprio(1);
#pragma unroll
        for (int n = 0; n < 4; ++n)
          sa[n] = __builtin_amdgcn_mfma_f32_16x16x32_bf16(kf[n], qf[m][ks], sa[n], 0, 0, 0);
        __builtin_amdgcn_s_setprio(0);
      }

      // ---- online softmax, log2 domain (row = q = l15; reduce over lh) ----
      float mx = sa[0][0];
#pragma unroll
      for (int n = 0; n < 4; ++n)
#pragma unroll
        for (int i = 0; i < 4; ++i) mx = fmaxf(mx, sa[n][i]);
      mx = fmaxf(mx, __shfl_xor(mx, 16));
      mx = fmaxf(mx, __shfl_xor(mx, 32));

      const bool skip = __all(mx <= mrun[m] + 8.0f);
      if (!skip) {
        const float nm = fmaxf(mrun[m], mx);
        const float corr = fexp2(mrun[m] - nm);
        lrun[m] *= corr;
        mrun[m] = nm;
        float c0 = __shfl(corr, lh * 4 + 0);
        float c1 = __shfl(corr, lh * 4 + 1);
        float c2 = __shfl(corr, lh * 4 + 2);
        float c3 = __shfl(corr, lh * 4 + 3);
        const f32x4 cv = {c0, c1, c2, c3};
#pragma unroll
        for (int no = 0; no < 5; ++no) oacc[m][no] *= cv;
      }

      float ps = 0.f;
#pragma unroll
      for (int n = 0; n < 4; ++n)
#pragma unroll
        for (int i = 0; i < 4; ++i) {
          const float p = fexp2(sa[n][i] - mrun[m]);
          sa[n][i] = p;
          ps += p;
        }
      ps += __shfl_xor(ps, 16);
      ps += __shfl_xor(ps, 32);
      lrun[m] += ps;

      // ---- P -> LDS: pack 4 consecutive keys via v_perm, ds_write_b64 ----
#pragma unroll
      for (int n = 0; n < 4; ++n) {
        unsigned w0 = __builtin_amdgcn_perm(__float_as_uint(sa[n][1]),
                                            __float_as_uint(sa[n][0]), 0x07060302u);
        unsigned w1 = __builtin_amdgcn_perm(__float_as_uint(sa[n][3]),
                                            __float_as_uint(sa[n][2]), 0x07060302u);
        uint2 w = {w0, w1};
        *(uint2*)((char*)Ps + wid * 2304 + l15 * 144 + n * 32 + lh * 8) = w;
      }

      // ---- PV ----
#pragma unroll
      for (int ks = 0; ks < 2; ++ks) {
        const short8 pa = *(const short8*)((const char*)Ps + wid * 2304 + l15 * 144 + ks * 64 + lh * 16);
        short8 vb[5];
        const int cc = ((ks << 2) + lh) ^ (l15 & 7);
#pragma unroll
        for (int no = 0; no < 5; ++no)
          vb[no] = *(const short8*)((const char*)Vs + no * 2048 + l15 * 128 + cc * 16);
        __builtin_amdgcn_s_setprio(1);
#pragma unroll
        for (int no = 0; no < 5; ++no)
          oacc[m][no] = __builtin_amdgcn_mfma_f32_16x16x32_bf16(pa, vb[no], oacc[m][no], 0, 0, 0);
        __builtin_amdgcn_s_setprio(0);
      }
    }
    __syncthreads();
  }

  // ---- epilogue ----
  const int b = bh >> 4, h = bh & 15;
#pragma unroll
  for (int m = 0; m < 2; ++m) {
    const float il = 1.0f / lrun[m];
    float inv[4];
#pragma unroll
    for (int i = 0; i < 4; ++i) inv[i] = __shfl(il, lh * 4 + i);
#pragma unroll
    for (int no = 0; no < 5; ++no) {
      const int d = no * 16 + l15;
      if (d < 72) {
#pragma unroll
        for (int i = 0; i < 4; ++i) {
          const int s = q0 + wid * 32 + m * 16 + lh * 4 + i;
          Og[((size_t)(b * 1024 + s)) * HIDDEN + h * 72 + d] = f2bf(oacc[m][no][i] * inv[i]);
        }
      }
    }
  }
}

// ---------------- launch ----------------
extern "C" void kernel_launch(void* const* d_in, const int* in_sizes, int n_in,
                              void* d_out, int out_size, void* d_ws, size_t ws_size,
                              hipStream_t stream) {
  const float* x  = (const float*)d_in[0];
  const float* wq = (const float*)d_in[1];
  const float* bq = (const float*)d_in[2];
  const float* wk = (const float*)d_in[3];
  const float* bk = (const float*)d_in[4];
  const float* wv = (const float*)d_in[5];
  const float* bv = (const float*)d_in[6];
  const float* wo = (const float*)d_in[7];
  const float* bo = (const float*)d_in[8];

  char* ws = (char*)d_ws;
  short* xb = (short*)ws;                    // 18,874,368 B (bf16 x; reused as attn out)
  short* wT = (short*)(ws + 18874368);       // 10,616,832 B
  short* Qb = (short*)(ws + 29491200);       // 18,874,368 B [bh][s][72]
  short* Kp = (short*)(ws + 48365568);       // 27,262,976 B [bh][s][104] padded
  short* Vt = (short*)(ws + 75628544);       // 20,971,520 B [bh][80][1024]
  const size_t WSZ = (size_t)HIDDEN * HIDDEN;

  k_cvtx<<<4608, 256, 0, stream>>>(x, xb);
  k_cvtw<<<dim3(18, 18, 4), 256, 0, stream>>>(wq, wk, wv, wo, wT);
  k_kpad<<<512, 256, 0, stream>>>(Kp);
  k_vzero<<<512, 256, 0, stream>>>(Vt);

  k_gemm_qkv<<<dim3(27, 32), 512, 0, stream>>>(xb, wT, bq, bk, bv, Qb, Kp, Vt);
  k_attn<<<1024, 256, 0, stream>>>(Qb, Kp, Vt, xb);
  k_gemm_o<<<dim3(9, 64), 256, 0, stream>>>(xb, wT + 3 * WSZ, bo, (float*)d_out);
}

// Round 9
// 217.181 us; speedup vs baseline: 1.1524x; 1.0496x over previous
//
#include <hip/hip_runtime.h>
#include <hip/hip_bf16.h>

#define HIDDEN 1152
#define NUM_HEADS 16
#define BATCH 8
#define SEQ 1024
#define MROWS (BATCH * SEQ)  // 8192
#define KSTRIDE 104          // padded K row length (shorts)
// log2(e) / sqrt(72): folded into Q so softmax can use exp2 directly
#define QSCALE_L2E (0.11785113019775793f * 1.4426950408889634f)

typedef __attribute__((ext_vector_type(8))) short short8;
typedef __attribute__((ext_vector_type(4))) float f32x4;

__device__ inline short f2bf(float x) {
  unsigned u = __float_as_uint(x);
  unsigned r = (u + 0x7FFFu + ((u >> 16) & 1u)) >> 16;
  return (short)(r & 0xFFFFu);
}

__device__ inline float fexp2(float x) { return __builtin_exp2f(x); }

__device__ inline void gload16(const void* g, void* l) {
  __builtin_amdgcn_global_load_lds(
      (const __attribute__((address_space(1))) void*)g,
      (__attribute__((address_space(3))) void*)l, 16, 0, 0);
}

// ---------------- fused prep: x->bf16 | K pad zero | Vt pad (ones row 72) ----
__global__ __launch_bounds__(256) void k_prep(const float* __restrict__ X,
                                              short* __restrict__ Xb,
                                              short* __restrict__ Kp,
                                              short* __restrict__ Vt) {
  const int bid = blockIdx.x;
  if (bid < 4608) {
    const size_t base = ((size_t)bid * 256 + threadIdx.x) * 8;
    float4 a = *(const float4*)(X + base);
    float4 b = *(const float4*)(X + base + 4);
    short8 o = {f2bf(a.x), f2bf(a.y), f2bf(a.z), f2bf(a.w),
                f2bf(b.x), f2bf(b.y), f2bf(b.z), f2bf(b.w)};
    *(short8*)(Xb + base) = o;
  } else if (bid < 5120) {
    const int r = (bid - 4608) * 256 + threadIdx.x;  // 131072 rows
    const short8 z = {0, 0, 0, 0, 0, 0, 0, 0};
    short* p = Kp + (size_t)r * KSTRIDE + 72;
    *(short8*)(p) = z;
    *(short8*)(p + 8) = z;
    *(short8*)(p + 16) = z;
  } else {
    const int t = (bid - 5120) * 256 + threadIdx.x;  // 131072 threads
    const int bh = t >> 10;
    const int off = (t & 1023) * 8;
    // rows 72..79 of Vt: row 72 = 1.0 (l-sum ones column), rows 73..79 = 0
    const short o = ((t & 1023) >> 7) == 0 ? (short)0x3F80 : (short)0;
    short8 v = {o, o, o, o, o, o, o, o};
    *(short8*)(Vt + (size_t)bh * 81920 + 73728 + off) = v;
  }
}

// ---------------- W [K,N] fp32 -> Wt [N,K] bf16 (4 matrices) ----------------
__global__ __launch_bounds__(256) void k_cvtw(const float* __restrict__ W0,
                                              const float* __restrict__ W1,
                                              const float* __restrict__ W2,
                                              const float* __restrict__ W3,
                                              short* __restrict__ Wt) {
  __shared__ float T[64][65];
  const float* W = (blockIdx.z == 0) ? W0 : (blockIdx.z == 1) ? W1
                 : (blockIdx.z == 2) ? W2 : W3;
  short* dst = Wt + (size_t)blockIdx.z * HIDDEN * HIDDEN;
  const int n0 = blockIdx.x * 64, k0 = blockIdx.y * 64;
  const int tid = threadIdx.x;
  for (int t = tid; t < 4096; t += 256) {
    int r = t >> 6, c = t & 63;
    T[r][c] = W[(size_t)(k0 + r) * HIDDEN + n0 + c];
  }
  __syncthreads();
  for (int t = tid; t < 4096; t += 256) {
    int r = t >> 6, c = t & 63;
    dst[(size_t)(n0 + r) * HIDDEN + k0 + c] = f2bf(T[c][r]);
  }
}

// ---------------- fused QKV GEMM: 256x128 tile, 512 threads (8 waves) --------
// Q: bf16 [bh][s][72] * QSCALE_L2E; K: bf16 [bh][s][104] padded; V: Vt[bh][80][1024]
__global__ __launch_bounds__(512) void k_gemm_qkv(
    const short* __restrict__ A, const short* __restrict__ Bt,
    const float* __restrict__ bq, const float* __restrict__ bk,
    const float* __restrict__ bv, short* __restrict__ Qb,
    short* __restrict__ Kp, short* __restrict__ Vt) {
  __shared__ __align__(16) short SM[24576];  // As(32KB) | Bs(16KB); Td in V-epilogue
  short* As = SM;          // [256][64] bf16, XOR-swizzled
  short* Bs = SM + 16384;  // [128][64]
  const int tid = threadIdx.x;
  const int lane = tid & 63;
  const int wid = tid >> 6;        // 0..7
  const int wr = wid >> 1, wc = wid & 1;
  // XCD-chunked bijective swizzle over 864 blocks (864 = 8*108)
  const int flat = blockIdx.y * 27 + blockIdx.x;
  const int rid = (flat & 7) * 108 + (flat >> 3);
  const int row0 = (rid / 27) << 8;      // 0..7936, step 256
  const int colTile = rid % 27;
  const int col0 = colTile << 7;
  const int l15 = lane & 15, lh = lane >> 4;
  const int lr8 = lane >> 3;
  const int csrc = ((lane & 7) ^ lr8) << 3;  // pre-swizzled source col (shorts)

  const f32x4 fz = {0.f, 0.f, 0.f, 0.f};
  f32x4 acc[4][4];
#pragma unroll
  for (int m = 0; m < 4; ++m)
#pragma unroll
    for (int n = 0; n < 4; ++n) acc[m][n] = fz;

  for (int k0 = 0; k0 < HIDDEN; k0 += 64) {
#pragma unroll
    for (int i = 0; i < 4; ++i) {  // A: 32 chunks of 1KB
      const int c = (wid << 2) + i;
      const int r = (c << 3) + lr8;
      gload16(A + (size_t)(row0 + r) * HIDDEN + k0 + csrc, (void*)(As + (c << 9)));
    }
#pragma unroll
    for (int i = 0; i < 2; ++i) {  // B: 16 chunks of 1KB
      const int c = (wid << 1) + i;
      const int r = (c << 3) + lr8;
      gload16(Bt + (size_t)(col0 + r) * HIDDEN + k0 + csrc, (void*)(Bs + (c << 9)));
    }
    __syncthreads();
#pragma unroll
    for (int ks = 0; ks < 2; ++ks) {
      short8 af[4], bfr[4];
#pragma unroll
      for (int m = 0; m < 4; ++m) {
        const int r = (wr << 6) + (m << 4) + l15;
        const int off = ((ks << 6) + (lh << 4)) ^ ((r & 7) << 4);
        af[m] = *(const short8*)((const char*)As + r * 128 + off);
      }
#pragma unroll
      for (int n = 0; n < 4; ++n) {
        const int r = (wc << 6) + (n << 4) + l15;
        const int off = ((ks << 6) + (lh << 4)) ^ ((r & 7) << 4);
        bfr[n] = *(const short8*)((const char*)Bs + r * 128 + off);
      }
      __builtin_amdgcn_s_setprio(1);
#pragma unroll
      for (int m = 0; m < 4; ++m)
#pragma unroll
        for (int n = 0; n < 4; ++n)
          acc[m][n] = __builtin_amdgcn_mfma_f32_16x16x32_bf16(af[m], bfr[n], acc[m][n], 0, 0, 0);
      __builtin_amdgcn_s_setprio(0);
    }
    __syncthreads();
  }

  const int cseg = colTile / 9;            // 0=Q 1=K 2=V (block-uniform)
  const int cwithin = (colTile % 9) << 7;  // col base within segment
  if (cseg < 2) {
    short* dst = (cseg == 0) ? Qb : Kp;
    const float* bias = (cseg == 0) ? bq : bk;
    const float scl = (cseg == 0) ? QSCALE_L2E : 1.0f;
    const int rstride = (cseg == 0) ? 72 : KSTRIDE;
#pragma unroll
    for (int n = 0; n < 4; ++n) {
      const int c = cwithin + (wc << 6) + (n << 4) + l15;
      const int h = c / 72;
      const int d = c - h * 72;
      const float bvx = bias[c];
#pragma unroll
      for (int m = 0; m < 4; ++m)
#pragma unroll
        for (int i = 0; i < 4; ++i) {
          const int r = row0 + (wr << 6) + (m << 4) + (lh << 2) + i;
          const int b = r >> 10, s = r & 1023;
          dst[(size_t)((((b << 4) + h) << 10) + s) * rstride + d] =
              f2bf((acc[m][n][i] + bvx) * scl);
        }
    }
  } else {
    // ---- V segment: LDS transpose -> coalesced [d][s] stores ----
    const int b = row0 >> 10;
    const int sb = row0 & 1023;
    short* Td = SM;  // 64 cols x 264 (rows 0..255 + pad)
#pragma unroll
    for (int p = 0; p < 2; ++p) {
      if (wc == p) {
#pragma unroll
        for (int n = 0; n < 4; ++n) {
          const int ci = n * 16 + l15;  // 0..63 within pass
          const float bvx = bv[cwithin + p * 64 + ci];
#pragma unroll
          for (int m = 0; m < 4; ++m) {
            const int r0 = (wr << 6) + (m << 4) + (lh << 2);
            short4 o;
            o.x = f2bf(acc[m][n][0] + bvx);
            o.y = f2bf(acc[m][n][1] + bvx);
            o.z = f2bf(acc[m][n][2] + bvx);
            o.w = f2bf(acc[m][n][3] + bvx);
            *(short4*)(Td + ci * 264 + r0) = o;
          }
        }
      }
      __syncthreads();
      {
        const int ci = tid >> 3;    // 0..63
        const int part = tid & 7;   // 0..7, 32 shorts each
        const int cg = cwithin + p * 64 + ci;
        const int h = cg / 72;
        const int d = cg - h * 72;
        short* dstp = Vt + (((size_t)(((b << 4) + h) * 80 + d)) << 10) + sb + part * 32;
        const short* srcp = Td + ci * 264 + part * 32;
#pragma unroll
        for (int k = 0; k < 4; ++k)
          *(short8*)(dstp + k * 8) = *(const short8*)(srcp + k * 8);
      }
      __syncthreads();
    }
  }
}

// ---------------- O GEMM: C fp32 = A[8192,1152]bf16 @ Wt[N,K]^T + bias -------
__global__ __launch_bounds__(256) void k_gemm_o(const short* __restrict__ A,
                                                const short* __restrict__ Bt,
                                                const float* __restrict__ bias,
                                                float* __restrict__ C) {
  __shared__ __align__(16) short As[8192];
  __shared__ __align__(16) short Bs[8192];
  const int tid = threadIdx.x;
  const int lane = tid & 63;
  const int wid = tid >> 6;
  const int wr = wid >> 1, wc = wid & 1;
  const int flat = blockIdx.y * 9 + blockIdx.x;
  const int rid = (flat & 7) * 72 + (flat >> 3);
  const int row0 = (rid / 9) << 7;
  const int col0 = (rid % 9) << 7;
  const int l15 = lane & 15, lh = lane >> 4;
  const int lr8 = lane >> 3;
  const int csrc = ((lane & 7) ^ lr8) << 3;

  const f32x4 fz = {0.f, 0.f, 0.f, 0.f};
  f32x4 acc[4][4];
#pragma unroll
  for (int m = 0; m < 4; ++m)
#pragma unroll
    for (int n = 0; n < 4; ++n) acc[m][n] = fz;

  for (int k0 = 0; k0 < HIDDEN; k0 += 64) {
#pragma unroll
    for (int i = 0; i < 4; ++i) {
      const int chunk = (wid << 2) + i;
      const int r = (chunk << 3) + lr8;
      gload16(A + (size_t)(row0 + r) * HIDDEN + k0 + csrc, (void*)(As + (chunk << 9)));
      gload16(Bt + (size_t)(col0 + r) * HIDDEN + k0 + csrc, (void*)(Bs + (chunk << 9)));
    }
    __syncthreads();
#pragma unroll
    for (int ks = 0; ks < 2; ++ks) {
      short8 af[4], bfr[4];
#pragma unroll
      for (int m = 0; m < 4; ++m) {
        const int r = (wr << 6) + (m << 4) + l15;
        const int off = ((ks << 6) + (lh << 4)) ^ ((r & 7) << 4);
        af[m] = *(const short8*)((const char*)As + r * 128 + off);
      }
#pragma unroll
      for (int n = 0; n < 4; ++n) {
        const int r = (wc << 6) + (n << 4) + l15;
        const int off = ((ks << 6) + (lh << 4)) ^ ((r & 7) << 4);
        bfr[n] = *(const short8*)((const char*)Bs + r * 128 + off);
      }
      __builtin_amdgcn_s_setprio(1);
#pragma unroll
      for (int m = 0; m < 4; ++m)
#pragma unroll
        for (int n = 0; n < 4; ++n)
          acc[m][n] = __builtin_amdgcn_mfma_f32_16x16x32_bf16(af[m], bfr[n], acc[m][n], 0, 0, 0);
      __builtin_amdgcn_s_setprio(0);
    }
    __syncthreads();
  }

#pragma unroll
  for (int n = 0; n < 4; ++n) {
    const int c = col0 + (wc << 6) + (n << 4) + l15;
    const float bvx = bias[c];
#pragma unroll
    for (int m = 0; m < 4; ++m)
#pragma unroll
      for (int i = 0; i < 4; ++i) {
        const int r = row0 + (wr << 6) + (m << 4) + (lh << 2) + i;
        C[(size_t)r * HIDDEN + c] = acc[m][n][i] + bvx;
      }
  }
}

// ---------------- Flash attention (VALU-trimmed: ones-col l-sum, lazy max) ---
// grid: 1024 blocks (XCD-chunked -> (qtile, bh)). 4 waves x 32 q-rows. KB=64.
__global__ __launch_bounds__(256, 4) void k_attn(const short* __restrict__ Qg,
                                                 const short* __restrict__ Kp,
                                                 const short* __restrict__ Vt,
                                                 short* __restrict__ Og) {
  __shared__ __align__(16) short Ks[64 * KSTRIDE];  // 13312 B, linear
  __shared__ __align__(16) short Vs[80 * 64];       // 10240 B, XOR-swizzled content
  __shared__ __align__(16) short Ps[4 * 16 * 72];   // 9216 B, per-wave 16 q-rows
  const int tid = threadIdx.x, lane = tid & 63, wid = tid >> 6;
  const int l15 = lane & 15, lh = lane >> 4;
  const int id = blockIdx.x;
  const int rid = (id & 7) * 128 + (id >> 3);
  const int bh = rid >> 3;
  const int q0 = (rid & 7) << 7;
  const short8 sz = {0, 0, 0, 0, 0, 0, 0, 0};
  const f32x4 fz = {0.f, 0.f, 0.f, 0.f};

  // Q fragments in registers (pre-scaled by log2e/sqrt(72) in the QKV GEMM)
  short8 qf[2][3];
#pragma unroll
  for (int m = 0; m < 2; ++m)
#pragma unroll
    for (int ks = 0; ks < 3; ++ks) {
      const int row = q0 + wid * 32 + m * 16 + l15;
      const int e0 = ks * 32 + lh * 8;
      if (e0 < 72)
        qf[m][ks] = *(const short8*)(Qg + ((size_t)bh * 1024 + row) * 72 + e0);
      else
        qf[m][ks] = sz;
    }

  float mrun[2] = {-1e30f, -1e30f};
  f32x4 oacc[2][5];  // oacc[m][4] col d=72 accumulates the softmax denominator
#pragma unroll
  for (int m = 0; m < 2; ++m)
#pragma unroll
    for (int no = 0; no < 5; ++no) oacc[m][no] = fz;

  const char* kgb = (const char*)Kp + ((size_t)bh * 1024) * (KSTRIDE * 2);
  const char* vgb = (const char*)Vt + (size_t)bh * 163840;

  for (int kt = 0; kt < 16; ++kt) {
    // ---- stage K tile: 13 contiguous 1KB wave-chunks ----
    const char* kg = kgb + (size_t)kt * 64 * (KSTRIDE * 2);
    for (int c = wid; c < 13; c += 4)
      gload16(kg + c * 1024 + lane * 16, (char*)Ks + c * 1024);
    // ---- stage V tile: linear LDS, pre-swizzled global source ----
    for (int c = wid; c < 10; c += 4) {
      const int p = c * 1024 + lane * 16;
      const int d = p >> 7;                       // 0..79
      const int sc16 = (lane & 7) ^ (d & 7);      // swizzled source chunk
      gload16(vgb + (size_t)d * 2048 + kt * 128 + sc16 * 16, (char*)Vs + c * 1024);
    }
    __syncthreads();

#pragma unroll
    for (int m = 0; m < 2; ++m) {
      // ---- QK^T swapped: lane holds 16 consecutive keys of q-row l15 ----
      f32x4 sa[4];
#pragma unroll
      for (int n = 0; n < 4; ++n) sa[n] = fz;
#pragma unroll
      for (int ks = 0; ks < 3; ++ks) {
        short8 kf[4];
#pragma unroll
        for (int n = 0; n < 4; ++n)
          kf[n] = *(const short8*)((const char*)Ks + (n * 16 + l15) * 208 + ks * 64 + lh * 16);
        __builtin_amdgcn_s_setprio(1);
#pragma unroll
        for (int n = 0; n < 4; ++n)
          sa[n] = __builtin_amdgcn_mfma_f32_16x16x32_bf16(kf[n], qf[m][ks], sa[n], 0, 0, 0);
        __builtin_amdgcn_s_setprio(0);
      }

      // ---- lane-local max via max3 tree; cross-lane reduce only on growth ----
#define M3(a, b, c) fmaxf(fmaxf((a), (b)), (c))
      float t0 = M3(sa[0][0], sa[0][1], sa[0][2]);
      float t1 = M3(sa[0][3], sa[1][0], sa[1][1]);
      float t2 = M3(sa[1][2], sa[1][3], sa[2][0]);
      float t3 = M3(sa[2][1], sa[2][2], sa[2][3]);
      float t4 = M3(sa[3][0], sa[3][1], sa[3][2]);
      float mx = fmaxf(M3(t0, t1, sa[3][3]), M3(t2, t3, t4));
#undef M3

      if (__any(mx > mrun[m] + 8.0f)) {
        mx = fmaxf(mx, __shfl_xor(mx, 16));
        mx = fmaxf(mx, __shfl_xor(mx, 32));
        const float nm = fmaxf(mrun[m], mx);
        const float corr = fexp2(mrun[m] - nm);
        mrun[m] = nm;
        float c0 = __shfl(corr, lh * 4 + 0);
        float c1 = __shfl(corr, lh * 4 + 1);
        float c2 = __shfl(corr, lh * 4 + 2);
        float c3 = __shfl(corr, lh * 4 + 3);
        const f32x4 cv = {c0, c1, c2, c3};
#pragma unroll
        for (int no = 0; no < 5; ++no) oacc[m][no] *= cv;  // rescales l-col too
      }

#pragma unroll
      for (int n = 0; n < 4; ++n)
#pragma unroll
        for (int i = 0; i < 4; ++i) sa[n][i] = fexp2(sa[n][i] - mrun[m]);

      // ---- P -> LDS: pack 4 consecutive keys via v_perm, ds_write_b64 ----
#pragma unroll
      for (int n = 0; n < 4; ++n) {
        unsigned w0 = __builtin_amdgcn_perm(__float_as_uint(sa[n][1]),
                                            __float_as_uint(sa[n][0]), 0x07060302u);
        unsigned w1 = __builtin_amdgcn_perm(__float_as_uint(sa[n][3]),
                                            __float_as_uint(sa[n][2]), 0x07060302u);
        uint2 w = {w0, w1};
        *(uint2*)((char*)Ps + wid * 2304 + l15 * 144 + n * 32 + lh * 8) = w;
      }

      // ---- PV (includes ones-column -> denominator in oacc[m][4], d=72) ----
#pragma unroll
      for (int ks = 0; ks < 2; ++ks) {
        const short8 pa = *(const short8*)((const char*)Ps + wid * 2304 + l15 * 144 + ks * 64 + lh * 16);
        short8 vb[5];
        const int cc = ((ks << 2) + lh) ^ (l15 & 7);
#pragma unroll
        for (int no = 0; no < 5; ++no)
          vb[no] = *(const short8*)((const char*)Vs + no * 2048 + l15 * 128 + cc * 16);
        __builtin_amdgcn_s_setprio(1);
#pragma unroll
        for (int no = 0; no < 5; ++no)
          oacc[m][no] = __builtin_amdgcn_mfma_f32_16x16x32_bf16(pa, vb[no], oacc[m][no], 0, 0, 0);
        __builtin_amdgcn_s_setprio(0);
      }
    }
    __syncthreads();
  }

  // ---- epilogue: l for rows lh*4+i lives in lane (l15=8, same lh), oacc[m][4][i]
  const int b = bh >> 4, h = bh & 15;
#pragma unroll
  for (int m = 0; m < 2; ++m) {
    float inv[4];
#pragma unroll
    for (int i = 0; i < 4; ++i)
      inv[i] = 1.0f / __shfl(oacc[m][4][i], (lane & 48) + 8);
#pragma unroll
    for (int no = 0; no < 5; ++no) {
      const int d = no * 16 + l15;
      if (d < 72) {
#pragma unroll
        for (int i = 0; i < 4; ++i) {
          const int s = q0 + wid * 32 + m * 16 + lh * 4 + i;
          Og[((size_t)(b * 1024 + s)) * HIDDEN + h * 72 + d] = f2bf(oacc[m][no][i] * inv[i]);
        }
      }
    }
  }
}

// ---------------- launch ----------------
extern "C" void kernel_launch(void* const* d_in, const int* in_sizes, int n_in,
                              void* d_out, int out_size, void* d_ws, size_t ws_size,
                              hipStream_t stream) {
  const float* x  = (const float*)d_in[0];
  const float* wq = (const float*)d_in[1];
  const float* bq = (const float*)d_in[2];
  const float* wk = (const float*)d_in[3];
  const float* bk = (const float*)d_in[4];
  const float* wv = (const float*)d_in[5];
  const float* bv = (const float*)d_in[6];
  const float* wo = (const float*)d_in[7];
  const float* bo = (const float*)d_in[8];

  char* ws = (char*)d_ws;
  short* xb = (short*)ws;                    // 18,874,368 B (bf16 x; reused as attn out)
  short* wT = (short*)(ws + 18874368);       // 10,616,832 B
  short* Qb = (short*)(ws + 29491200);       // 18,874,368 B [bh][s][72]
  short* Kp = (short*)(ws + 48365568);       // 27,262,976 B [bh][s][104] padded
  short* Vt = (short*)(ws + 75628544);       // 20,971,520 B [bh][80][1024]
  const size_t WSZ = (size_t)HIDDEN * HIDDEN;

  k_prep<<<5632, 256, 0, stream>>>(x, xb, Kp, Vt);
  k_cvtw<<<dim3(18, 18, 4), 256, 0, stream>>>(wq, wk, wv, wo, wT);

  k_gemm_qkv<<<dim3(27, 32), 512, 0, stream>>>(xb, wT, bq, bk, bv, Qb, Kp, Vt);
  k_attn<<<1024, 256, 0, stream>>>(Qb, Kp, Vt, xb);
  k_gemm_o<<<dim3(9, 64), 256, 0, stream>>>(xb, wT + 3 * WSZ, bo, (float*)d_out);
}

// Round 10
// 209.174 us; speedup vs baseline: 1.1965x; 1.0383x over previous
//
#include <hip/hip_runtime.h>
#include <hip/hip_bf16.h>

#define HIDDEN 1152
#define NUM_HEADS 16
#define BATCH 8
#define SEQ 1024
#define MROWS (BATCH * SEQ)  // 8192
#define KSTRIDE 104          // padded K row length (shorts)
// log2(e) / sqrt(72): folded into Q so softmax can use exp2 directly
#define QSCALE_L2E (0.11785113019775793f * 1.4426950408889634f)

typedef __attribute__((ext_vector_type(8))) short short8;
typedef __attribute__((ext_vector_type(4))) float f32x4;

__device__ inline short f2bf(float x) {
  unsigned u = __float_as_uint(x);
  unsigned r = (u + 0x7FFFu + ((u >> 16) & 1u)) >> 16;
  return (short)(r & 0xFFFFu);
}

__device__ inline float fexp2(float x) { return __builtin_exp2f(x); }

__device__ inline void gload16(const void* g, void* l) {
  __builtin_amdgcn_global_load_lds(
      (const __attribute__((address_space(1))) void*)g,
      (__attribute__((address_space(3))) void*)l, 16, 0, 0);
}

// ---------------- fused prep: x->bf16 | K pad zero | Vt pad (ones row 72) ----
__global__ __launch_bounds__(256) void k_prep(const float* __restrict__ X,
                                              short* __restrict__ Xb,
                                              short* __restrict__ Kp,
                                              short* __restrict__ Vt) {
  const int bid = blockIdx.x;
  if (bid < 4608) {
    const size_t base = ((size_t)bid * 256 + threadIdx.x) * 8;
    float4 a = *(const float4*)(X + base);
    float4 b = *(const float4*)(X + base + 4);
    short8 o = {f2bf(a.x), f2bf(a.y), f2bf(a.z), f2bf(a.w),
                f2bf(b.x), f2bf(b.y), f2bf(b.z), f2bf(b.w)};
    *(short8*)(Xb + base) = o;
  } else if (bid < 5120) {
    const int r = (bid - 4608) * 256 + threadIdx.x;  // 131072 rows
    const short8 z = {0, 0, 0, 0, 0, 0, 0, 0};
    short* p = Kp + (size_t)r * KSTRIDE + 72;
    *(short8*)(p) = z;
    *(short8*)(p + 8) = z;
    *(short8*)(p + 16) = z;
  } else {
    const int t = (bid - 5120) * 256 + threadIdx.x;  // 131072 threads
    const int bh = t >> 10;
    const int off = (t & 1023) * 8;
    // rows 72..79 of Vt: row 72 = 1.0 (l-sum ones column), rows 73..79 = 0
    const short o = ((t & 1023) >> 7) == 0 ? (short)0x3F80 : (short)0;
    short8 v = {o, o, o, o, o, o, o, o};
    *(short8*)(Vt + (size_t)bh * 81920 + 73728 + off) = v;
  }
}

// ---------------- W [K,N] fp32 -> Wt [N,K] bf16 (4 matrices) ----------------
__global__ __launch_bounds__(256) void k_cvtw(const float* __restrict__ W0,
                                              const float* __restrict__ W1,
                                              const float* __restrict__ W2,
                                              const float* __restrict__ W3,
                                              short* __restrict__ Wt) {
  __shared__ float T[64][65];
  const float* W = (blockIdx.z == 0) ? W0 : (blockIdx.z == 1) ? W1
                 : (blockIdx.z == 2) ? W2 : W3;
  short* dst = Wt + (size_t)blockIdx.z * HIDDEN * HIDDEN;
  const int n0 = blockIdx.x * 64, k0 = blockIdx.y * 64;
  const int tid = threadIdx.x;
  for (int t = tid; t < 4096; t += 256) {
    int r = t >> 6, c = t & 63;
    T[r][c] = W[(size_t)(k0 + r) * HIDDEN + n0 + c];
  }
  __syncthreads();
  for (int t = tid; t < 4096; t += 256) {
    int r = t >> 6, c = t & 63;
    dst[(size_t)(n0 + r) * HIDDEN + k0 + c] = f2bf(T[c][r]);
  }
}

// ---------------- fused QKV GEMM: 256x128 tile, 512 threads (8 waves) --------
// Q: bf16 [bh][s][72] * QSCALE_L2E; K: bf16 [bh][s][104] padded; V: Vt[bh][80][1024]
__global__ __launch_bounds__(512) void k_gemm_qkv(
    const short* __restrict__ A, const short* __restrict__ Bt,
    const float* __restrict__ bq, const float* __restrict__ bk,
    const float* __restrict__ bv, short* __restrict__ Qb,
    short* __restrict__ Kp, short* __restrict__ Vt) {
  __shared__ __align__(16) short SM[24576];  // As(32KB) | Bs(16KB); Td in V-epilogue
  short* As = SM;          // [256][64] bf16, XOR-swizzled
  short* Bs = SM + 16384;  // [128][64]
  const int tid = threadIdx.x;
  const int lane = tid & 63;
  const int wid = tid >> 6;        // 0..7
  const int wr = wid >> 1, wc = wid & 1;
  // XCD-chunked bijective swizzle over 864 blocks (864 = 8*108)
  const int flat = blockIdx.y * 27 + blockIdx.x;
  const int rid = (flat & 7) * 108 + (flat >> 3);
  const int row0 = (rid / 27) << 8;      // 0..7936, step 256
  const int colTile = rid % 27;
  const int col0 = colTile << 7;
  const int l15 = lane & 15, lh = lane >> 4;
  const int lr8 = lane >> 3;
  const int csrc = ((lane & 7) ^ lr8) << 3;  // pre-swizzled source col (shorts)

  const f32x4 fz = {0.f, 0.f, 0.f, 0.f};
  f32x4 acc[4][4];
#pragma unroll
  for (int m = 0; m < 4; ++m)
#pragma unroll
    for (int n = 0; n < 4; ++n) acc[m][n] = fz;

  for (int k0 = 0; k0 < HIDDEN; k0 += 64) {
#pragma unroll
    for (int i = 0; i < 4; ++i) {  // A: 32 chunks of 1KB
      const int c = (wid << 2) + i;
      const int r = (c << 3) + lr8;
      gload16(A + (size_t)(row0 + r) * HIDDEN + k0 + csrc, (void*)(As + (c << 9)));
    }
#pragma unroll
    for (int i = 0; i < 2; ++i) {  // B: 16 chunks of 1KB
      const int c = (wid << 1) + i;
      const int r = (c << 3) + lr8;
      gload16(Bt + (size_t)(col0 + r) * HIDDEN + k0 + csrc, (void*)(Bs + (c << 9)));
    }
    __syncthreads();
#pragma unroll
    for (int ks = 0; ks < 2; ++ks) {
      short8 af[4], bfr[4];
#pragma unroll
      for (int m = 0; m < 4; ++m) {
        const int r = (wr << 6) + (m << 4) + l15;
        const int off = ((ks << 6) + (lh << 4)) ^ ((r & 7) << 4);
        af[m] = *(const short8*)((const char*)As + r * 128 + off);
      }
#pragma unroll
      for (int n = 0; n < 4; ++n) {
        const int r = (wc << 6) + (n << 4) + l15;
        const int off = ((ks << 6) + (lh << 4)) ^ ((r & 7) << 4);
        bfr[n] = *(const short8*)((const char*)Bs + r * 128 + off);
      }
      __builtin_amdgcn_s_setprio(1);
#pragma unroll
      for (int m = 0; m < 4; ++m)
#pragma unroll
        for (int n = 0; n < 4; ++n)
          acc[m][n] = __builtin_amdgcn_mfma_f32_16x16x32_bf16(af[m], bfr[n], acc[m][n], 0, 0, 0);
      __builtin_amdgcn_s_setprio(0);
    }
    __syncthreads();
  }

  const int cseg = colTile / 9;            // 0=Q 1=K 2=V (block-uniform)
  const int cwithin = (colTile % 9) << 7;  // col base within segment
  if (cseg < 2) {
    short* dst = (cseg == 0) ? Qb : Kp;
    const float* bias = (cseg == 0) ? bq : bk;
    const float scl = (cseg == 0) ? QSCALE_L2E : 1.0f;
    const int rstride = (cseg == 0) ? 72 : KSTRIDE;
#pragma unroll
    for (int n = 0; n < 4; ++n) {
      const int c = cwithin + (wc << 6) + (n << 4) + l15;
      const int h = c / 72;
      const int d = c - h * 72;
      const float bvx = bias[c];
#pragma unroll
      for (int m = 0; m < 4; ++m)
#pragma unroll
        for (int i = 0; i < 4; ++i) {
          const int r = row0 + (wr << 6) + (m << 4) + (lh << 2) + i;
          const int b = r >> 10, s = r & 1023;
          dst[(size_t)((((b << 4) + h) << 10) + s) * rstride + d] =
              f2bf((acc[m][n][i] + bvx) * scl);
        }
    }
  } else {
    // ---- V segment: LDS transpose -> coalesced [d][s] stores ----
    const int b = row0 >> 10;
    const int sb = row0 & 1023;
    short* Td = SM;  // 64 cols x 264 (rows 0..255 + pad)
#pragma unroll
    for (int p = 0; p < 2; ++p) {
      if (wc == p) {
#pragma unroll
        for (int n = 0; n < 4; ++n) {
          const int ci = n * 16 + l15;  // 0..63 within pass
          const float bvx = bv[cwithin + p * 64 + ci];
#pragma unroll
          for (int m = 0; m < 4; ++m) {
            const int r0 = (wr << 6) + (m << 4) + (lh << 2);
            short4 o;
            o.x = f2bf(acc[m][n][0] + bvx);
            o.y = f2bf(acc[m][n][1] + bvx);
            o.z = f2bf(acc[m][n][2] + bvx);
            o.w = f2bf(acc[m][n][3] + bvx);
            *(short4*)(Td + ci * 264 + r0) = o;
          }
        }
      }
      __syncthreads();
      {
        const int ci = tid >> 3;    // 0..63
        const int part = tid & 7;   // 0..7, 32 shorts each
        const int cg = cwithin + p * 64 + ci;
        const int h = cg / 72;
        const int d = cg - h * 72;
        short* dstp = Vt + (((size_t)(((b << 4) + h) * 80 + d)) << 10) + sb + part * 32;
        const short* srcp = Td + ci * 264 + part * 32;
#pragma unroll
        for (int k = 0; k < 4; ++k)
          *(short8*)(dstp + k * 8) = *(const short8*)(srcp + k * 8);
      }
      __syncthreads();
    }
  }
}

// ---------------- O GEMM: 256x128 tile, 512 threads, fp32 out ---------------
__global__ __launch_bounds__(512) void k_gemm_o(const short* __restrict__ A,
                                                const short* __restrict__ Bt,
                                                const float* __restrict__ bias,
                                                float* __restrict__ C) {
  __shared__ __align__(16) short SM[24576];
  short* As = SM;          // [256][64]
  short* Bs = SM + 16384;  // [128][64]
  const int tid = threadIdx.x;
  const int lane = tid & 63;
  const int wid = tid >> 6;
  const int wr = wid >> 1, wc = wid & 1;
  // XCD-chunked bijective swizzle over 288 blocks (288 = 8*36)
  const int flat = blockIdx.y * 9 + blockIdx.x;
  const int rid = (flat & 7) * 36 + (flat >> 3);
  const int row0 = (rid / 9) << 8;
  const int col0 = (rid % 9) << 7;
  const int l15 = lane & 15, lh = lane >> 4;
  const int lr8 = lane >> 3;
  const int csrc = ((lane & 7) ^ lr8) << 3;

  const f32x4 fz = {0.f, 0.f, 0.f, 0.f};
  f32x4 acc[4][4];
#pragma unroll
  for (int m = 0; m < 4; ++m)
#pragma unroll
    for (int n = 0; n < 4; ++n) acc[m][n] = fz;

  for (int k0 = 0; k0 < HIDDEN; k0 += 64) {
#pragma unroll
    for (int i = 0; i < 4; ++i) {  // A: 32 chunks of 1KB
      const int c = (wid << 2) + i;
      const int r = (c << 3) + lr8;
      gload16(A + (size_t)(row0 + r) * HIDDEN + k0 + csrc, (void*)(As + (c << 9)));
    }
#pragma unroll
    for (int i = 0; i < 2; ++i) {  // B: 16 chunks of 1KB
      const int c = (wid << 1) + i;
      const int r = (c << 3) + lr8;
      gload16(Bt + (size_t)(col0 + r) * HIDDEN + k0 + csrc, (void*)(Bs + (c << 9)));
    }
    __syncthreads();
#pragma unroll
    for (int ks = 0; ks < 2; ++ks) {
      short8 af[4], bfr[4];
#pragma unroll
      for (int m = 0; m < 4; ++m) {
        const int r = (wr << 6) + (m << 4) + l15;
        const int off = ((ks << 6) + (lh << 4)) ^ ((r & 7) << 4);
        af[m] = *(const short8*)((const char*)As + r * 128 + off);
      }
#pragma unroll
      for (int n = 0; n < 4; ++n) {
        const int r = (wc << 6) + (n << 4) + l15;
        const int off = ((ks << 6) + (lh << 4)) ^ ((r & 7) << 4);
        bfr[n] = *(const short8*)((const char*)Bs + r * 128 + off);
      }
      __builtin_amdgcn_s_setprio(1);
#pragma unroll
      for (int m = 0; m < 4; ++m)
#pragma unroll
        for (int n = 0; n < 4; ++n)
          acc[m][n] = __builtin_amdgcn_mfma_f32_16x16x32_bf16(af[m], bfr[n], acc[m][n], 0, 0, 0);
      __builtin_amdgcn_s_setprio(0);
    }
    __syncthreads();
  }

#pragma unroll
  for (int n = 0; n < 4; ++n) {
    const int c = col0 + (wc << 6) + (n << 4) + l15;
    const float bvx = bias[c];
#pragma unroll
    for (int m = 0; m < 4; ++m)
#pragma unroll
      for (int i = 0; i < 4; ++i) {
        const int r = row0 + (wr << 6) + (m << 4) + (lh << 2) + i;
        C[(size_t)r * HIDDEN + c] = acc[m][n][i] + bvx;
      }
  }
}

// ---------------- Flash attention (2-chain pipelined QK^T, ones-col l-sum) ---
// grid: 1024 blocks (XCD-chunked -> (qtile, bh)). 4 waves x 32 q-rows. KB=64.
__global__ __launch_bounds__(256, 4) void k_attn(const short* __restrict__ Qg,
                                                 const short* __restrict__ Kp,
                                                 const short* __restrict__ Vt,
                                                 short* __restrict__ Og) {
  __shared__ __align__(16) short Ks[64 * KSTRIDE];  // 13312 B, linear
  __shared__ __align__(16) short Vs[80 * 64];       // 10240 B, XOR-swizzled content
  __shared__ __align__(16) short Ps[4 * 16 * 72];   // 9216 B, per-wave 16 q-rows
  const int tid = threadIdx.x, lane = tid & 63, wid = tid >> 6;
  const int l15 = lane & 15, lh = lane >> 4;
  const int id = blockIdx.x;
  const int rid = (id & 7) * 128 + (id >> 3);
  const int bh = rid >> 3;
  const int q0 = (rid & 7) << 7;
  const short8 sz = {0, 0, 0, 0, 0, 0, 0, 0};
  const f32x4 fz = {0.f, 0.f, 0.f, 0.f};

  // Q fragments in registers (pre-scaled by log2e/sqrt(72) in the QKV GEMM)
  short8 qf[2][3];
#pragma unroll
  for (int m = 0; m < 2; ++m)
#pragma unroll
    for (int ks = 0; ks < 3; ++ks) {
      const int row = q0 + wid * 32 + m * 16 + l15;
      const int e0 = ks * 32 + lh * 8;
      if (e0 < 72)
        qf[m][ks] = *(const short8*)(Qg + ((size_t)bh * 1024 + row) * 72 + e0);
      else
        qf[m][ks] = sz;
    }

  float mrun[2] = {-1e30f, -1e30f};
  f32x4 oacc[2][5];  // oacc[m][4] col d=72 accumulates the softmax denominator
#pragma unroll
  for (int m = 0; m < 2; ++m)
#pragma unroll
    for (int no = 0; no < 5; ++no) oacc[m][no] = fz;

  const char* kgb = (const char*)Kp + ((size_t)bh * 1024) * (KSTRIDE * 2);
  const char* vgb = (const char*)Vt + (size_t)bh * 163840;
  short* psw = Ps + wid * 1152;

  for (int kt = 0; kt < 16; ++kt) {
    // ---- stage K tile: 13 contiguous 1KB wave-chunks ----
    const char* kg = kgb + (size_t)kt * 64 * (KSTRIDE * 2);
    for (int c = wid; c < 13; c += 4)
      gload16(kg + c * 1024 + lane * 16, (char*)Ks + c * 1024);
    // ---- stage V tile: linear LDS, pre-swizzled global source ----
    for (int c = wid; c < 10; c += 4) {
      const int p = c * 1024 + lane * 16;
      const int d = p >> 7;                       // 0..79
      const int sc16 = (lane & 7) ^ (d & 7);      // swizzled source chunk
      gload16(vgb + (size_t)d * 2048 + kt * 128 + sc16 * 16, (char*)Vs + c * 1024);
    }
    __syncthreads();

    // ---- QK^T for BOTH m-halves (shared kf loads; independent MFMA chains) --
    f32x4 sa[2][4];
#pragma unroll
    for (int m = 0; m < 2; ++m)
#pragma unroll
      for (int n = 0; n < 4; ++n) sa[m][n] = fz;
#pragma unroll
    for (int ks = 0; ks < 3; ++ks) {
      short8 kf[4];
#pragma unroll
      for (int n = 0; n < 4; ++n)
        kf[n] = *(const short8*)((const char*)Ks + (n * 16 + l15) * 208 + ks * 64 + lh * 16);
      __builtin_amdgcn_s_setprio(1);
#pragma unroll
      for (int n = 0; n < 4; ++n)
        sa[0][n] = __builtin_amdgcn_mfma_f32_16x16x32_bf16(kf[n], qf[0][ks], sa[0][n], 0, 0, 0);
#pragma unroll
      for (int n = 0; n < 4; ++n)
        sa[1][n] = __builtin_amdgcn_mfma_f32_16x16x32_bf16(kf[n], qf[1][ks], sa[1][n], 0, 0, 0);
      __builtin_amdgcn_s_setprio(0);
    }

    // ---- per-m: softmax -> pack -> PV (m1's regs live during m0's VALU) ----
#pragma unroll
    for (int m = 0; m < 2; ++m) {
#define M3(a, b, c) fmaxf(fmaxf((a), (b)), (c))
      float t0 = M3(sa[m][0][0], sa[m][0][1], sa[m][0][2]);
      float t1 = M3(sa[m][0][3], sa[m][1][0], sa[m][1][1]);
      float t2 = M3(sa[m][1][2], sa[m][1][3], sa[m][2][0]);
      float t3 = M3(sa[m][2][1], sa[m][2][2], sa[m][2][3]);
      float t4 = M3(sa[m][3][0], sa[m][3][1], sa[m][3][2]);
      float mx = fmaxf(M3(t0, t1, sa[m][3][3]), M3(t2, t3, t4));
#undef M3

      if (__any(mx > mrun[m] + 8.0f)) {
        mx = fmaxf(mx, __shfl_xor(mx, 16));
        mx = fmaxf(mx, __shfl_xor(mx, 32));
        const float nm = fmaxf(mrun[m], mx);
        const float corr = fexp2(mrun[m] - nm);
        mrun[m] = nm;
        float c0 = __shfl(corr, lh * 4 + 0);
        float c1 = __shfl(corr, lh * 4 + 1);
        float c2 = __shfl(corr, lh * 4 + 2);
        float c3 = __shfl(corr, lh * 4 + 3);
        const f32x4 cv = {c0, c1, c2, c3};
#pragma unroll
        for (int no = 0; no < 5; ++no) oacc[m][no] *= cv;  // rescales l-col too
      }

#pragma unroll
      for (int n = 0; n < 4; ++n)
#pragma unroll
        for (int i = 0; i < 4; ++i) sa[m][n][i] = fexp2(sa[m][n][i] - mrun[m]);

      // ---- P -> per-wave LDS (bf16 pack via v_perm, ds_write_b64) ----
#pragma unroll
      for (int n = 0; n < 4; ++n) {
        unsigned w0 = __builtin_amdgcn_perm(__float_as_uint(sa[m][n][1]),
                                            __float_as_uint(sa[m][n][0]), 0x07060302u);
        unsigned w1 = __builtin_amdgcn_perm(__float_as_uint(sa[m][n][3]),
                                            __float_as_uint(sa[m][n][2]), 0x07060302u);
        uint2 w = {w0, w1};
        *(uint2*)((char*)psw + l15 * 144 + n * 32 + lh * 8) = w;
      }

      // ---- PV (includes ones-column -> denominator in oacc[m][4], d=72) ----
#pragma unroll
      for (int ks = 0; ks < 2; ++ks) {
        const short8 pa = *(const short8*)((const char*)psw + l15 * 144 + ks * 64 + lh * 16);
        short8 vb[5];
        const int cc = ((ks << 2) + lh) ^ (l15 & 7);
#pragma unroll
        for (int no = 0; no < 5; ++no)
          vb[no] = *(const short8*)((const char*)Vs + no * 2048 + l15 * 128 + cc * 16);
        __builtin_amdgcn_s_setprio(1);
#pragma unroll
        for (int no = 0; no < 5; ++no)
          oacc[m][no] = __builtin_amdgcn_mfma_f32_16x16x32_bf16(pa, vb[no], oacc[m][no], 0, 0, 0);
        __builtin_amdgcn_s_setprio(0);
      }
    }
    __syncthreads();
  }

  // ---- epilogue: l for rows lh*4+i lives in lane (l15=8, same lh), oacc[m][4][i]
  const int b = bh >> 4, h = bh & 15;
#pragma unroll
  for (int m = 0; m < 2; ++m) {
    float inv[4];
#pragma unroll
    for (int i = 0; i < 4; ++i)
      inv[i] = 1.0f / __shfl(oacc[m][4][i], (lane & 48) + 8);
#pragma unroll
    for (int no = 0; no < 5; ++no) {
      const int d = no * 16 + l15;
      if (d < 72) {
#pragma unroll
        for (int i = 0; i < 4; ++i) {
          const int s = q0 + wid * 32 + m * 16 + lh * 4 + i;
          Og[((size_t)(b * 1024 + s)) * HIDDEN + h * 72 + d] = f2bf(oacc[m][no][i] * inv[i]);
        }
      }
    }
  }
}

// ---------------- launch ----------------
extern "C" void kernel_launch(void* const* d_in, const int* in_sizes, int n_in,
                              void* d_out, int out_size, void* d_ws, size_t ws_size,
                              hipStream_t stream) {
  const float* x  = (const float*)d_in[0];
  const float* wq = (const float*)d_in[1];
  const float* bq = (const float*)d_in[2];
  const float* wk = (const float*)d_in[3];
  const float* bk = (const float*)d_in[4];
  const float* wv = (const float*)d_in[5];
  const float* bv = (const float*)d_in[6];
  const float* wo = (const float*)d_in[7];
  const float* bo = (const float*)d_in[8];

  char* ws = (char*)d_ws;
  short* xb = (short*)ws;                    // 18,874,368 B (bf16 x; reused as attn out)
  short* wT = (short*)(ws + 18874368);       // 10,616,832 B
  short* Qb = (short*)(ws + 29491200);       // 18,874,368 B [bh][s][72]
  short* Kp = (short*)(ws + 48365568);       // 27,262,976 B [bh][s][104] padded
  short* Vt = (short*)(ws + 75628544);       // 20,971,520 B [bh][80][1024]
  const size_t WSZ = (size_t)HIDDEN * HIDDEN;

  k_prep<<<5632, 256, 0, stream>>>(x, xb, Kp, Vt);
  k_cvtw<<<dim3(18, 18, 4), 256, 0, stream>>>(wq, wk, wv, wo, wT);

  k_gemm_qkv<<<dim3(27, 32), 512, 0, stream>>>(xb, wT, bq, bk, bv, Qb, Kp, Vt);
  k_attn<<<1024, 256, 0, stream>>>(Qb, Kp, Vt, xb);
  k_gemm_o<<<dim3(9, 32), 512, 0, stream>>>(xb, wT + 3 * WSZ, bo, (float*)d_out);
}

// Round 11
// 190.759 us; speedup vs baseline: 1.3120x; 1.0965x over previous
//
#include <hip/hip_runtime.h>
#include <hip/hip_bf16.h>

#define HIDDEN 1152
#define NUM_HEADS 16
#define BATCH 8
#define SEQ 1024
#define MROWS (BATCH * SEQ)  // 8192
#define KSTRIDE 104          // padded K row length (shorts)
// log2(e) / sqrt(72): folded into Q so softmax can use exp2 directly
#define QSCALE_L2E (0.11785113019775793f * 1.4426950408889634f)

typedef __attribute__((ext_vector_type(8))) short short8;
typedef __attribute__((ext_vector_type(4))) float f32x4;

__device__ inline short f2bf(float x) {
  unsigned u = __float_as_uint(x);
  unsigned r = (u + 0x7FFFu + ((u >> 16) & 1u)) >> 16;
  return (short)(r & 0xFFFFu);
}

__device__ inline float fexp2(float x) { return __builtin_exp2f(x); }

__device__ inline void gload16(const void* g, void* l) {
  __builtin_amdgcn_global_load_lds(
      (const __attribute__((address_space(1))) void*)g,
      (__attribute__((address_space(3))) void*)l, 16, 0, 0);
}

// ------- fused prep: x->bf16 | K pad (col72=-8, rest 0) | Vt pad (row72=1) ---
__global__ __launch_bounds__(256) void k_prep(const float* __restrict__ X,
                                              short* __restrict__ Xb,
                                              short* __restrict__ Kp,
                                              short* __restrict__ Vt) {
  const int bid = blockIdx.x;
  if (bid < 4608) {
    const size_t base = ((size_t)bid * 256 + threadIdx.x) * 8;
    float4 a = *(const float4*)(X + base);
    float4 b = *(const float4*)(X + base + 4);
    short8 o = {f2bf(a.x), f2bf(a.y), f2bf(a.z), f2bf(a.w),
                f2bf(b.x), f2bf(b.y), f2bf(b.z), f2bf(b.w)};
    *(short8*)(Xb + base) = o;
  } else if (bid < 5120) {
    const int r = (bid - 4608) * 256 + threadIdx.x;  // 131072 rows
    // col 72 = bf16(-8.0) -> with Q slot72 = 1.0, every score gets -8 shift
    const short8 z0 = {(short)0xC100, 0, 0, 0, 0, 0, 0, 0};
    const short8 z = {0, 0, 0, 0, 0, 0, 0, 0};
    short* p = Kp + (size_t)r * KSTRIDE + 72;
    *(short8*)(p) = z0;
    *(short8*)(p + 8) = z;
    *(short8*)(p + 16) = z;
  } else {
    const int t = (bid - 5120) * 256 + threadIdx.x;  // 131072 threads
    const int bh = t >> 10;
    const int off = (t & 1023) * 8;
    // rows 72..79 of Vt: row 72 = 1.0 (denominator ones column), 73..79 = 0
    const short o = ((t & 1023) >> 7) == 0 ? (short)0x3F80 : (short)0;
    short8 v = {o, o, o, o, o, o, o, o};
    *(short8*)(Vt + (size_t)bh * 81920 + 73728 + off) = v;
  }
}

// ---------------- W [K,N] fp32 -> Wt [N,K] bf16 (4 matrices) ----------------
__global__ __launch_bounds__(256) void k_cvtw(const float* __restrict__ W0,
                                              const float* __restrict__ W1,
                                              const float* __restrict__ W2,
                                              const float* __restrict__ W3,
                                              short* __restrict__ Wt) {
  __shared__ float T[64][65];
  const float* W = (blockIdx.z == 0) ? W0 : (blockIdx.z == 1) ? W1
                 : (blockIdx.z == 2) ? W2 : W3;
  short* dst = Wt + (size_t)blockIdx.z * HIDDEN * HIDDEN;
  const int n0 = blockIdx.x * 64, k0 = blockIdx.y * 64;
  const int tid = threadIdx.x;
  for (int t = tid; t < 4096; t += 256) {
    int r = t >> 6, c = t & 63;
    T[r][c] = W[(size_t)(k0 + r) * HIDDEN + n0 + c];
  }
  __syncthreads();
  for (int t = tid; t < 4096; t += 256) {
    int r = t >> 6, c = t & 63;
    dst[(size_t)(n0 + r) * HIDDEN + k0 + c] = f2bf(T[c][r]);
  }
}

// ---------------- fused QKV GEMM: 256x128 tile, 512 threads (8 waves) --------
__global__ __launch_bounds__(512) void k_gemm_qkv(
    const short* __restrict__ A, const short* __restrict__ Bt,
    const float* __restrict__ bq, const float* __restrict__ bk,
    const float* __restrict__ bv, short* __restrict__ Qb,
    short* __restrict__ Kp, short* __restrict__ Vt) {
  __shared__ __align__(16) short SM[24576];  // As(32KB) | Bs(16KB); Td in V-epilogue
  short* As = SM;          // [256][64] bf16, XOR-swizzled
  short* Bs = SM + 16384;  // [128][64]
  const int tid = threadIdx.x;
  const int lane = tid & 63;
  const int wid = tid >> 6;        // 0..7
  const int wr = wid >> 1, wc = wid & 1;
  // XCD-chunked bijective swizzle over 864 blocks (864 = 8*108)
  const int flat = blockIdx.y * 27 + blockIdx.x;
  const int rid = (flat & 7) * 108 + (flat >> 3);
  const int row0 = (rid / 27) << 8;      // 0..7936, step 256
  const int colTile = rid % 27;
  const int col0 = colTile << 7;
  const int l15 = lane & 15, lh = lane >> 4;
  const int lr8 = lane >> 3;
  const int csrc = ((lane & 7) ^ lr8) << 3;  // pre-swizzled source col (shorts)

  const f32x4 fz = {0.f, 0.f, 0.f, 0.f};
  f32x4 acc[4][4];
#pragma unroll
  for (int m = 0; m < 4; ++m)
#pragma unroll
    for (int n = 0; n < 4; ++n) acc[m][n] = fz;

  for (int k0 = 0; k0 < HIDDEN; k0 += 64) {
#pragma unroll
    for (int i = 0; i < 4; ++i) {  // A: 32 chunks of 1KB
      const int c = (wid << 2) + i;
      const int r = (c << 3) + lr8;
      gload16(A + (size_t)(row0 + r) * HIDDEN + k0 + csrc, (void*)(As + (c << 9)));
    }
#pragma unroll
    for (int i = 0; i < 2; ++i) {  // B: 16 chunks of 1KB
      const int c = (wid << 1) + i;
      const int r = (c << 3) + lr8;
      gload16(Bt + (size_t)(col0 + r) * HIDDEN + k0 + csrc, (void*)(Bs + (c << 9)));
    }
    __syncthreads();
#pragma unroll
    for (int ks = 0; ks < 2; ++ks) {
      short8 af[4], bfr[4];
#pragma unroll
      for (int m = 0; m < 4; ++m) {
        const int r = (wr << 6) + (m << 4) + l15;
        const int off = ((ks << 6) + (lh << 4)) ^ ((r & 7) << 4);
        af[m] = *(const short8*)((const char*)As + r * 128 + off);
      }
#pragma unroll
      for (int n = 0; n < 4; ++n) {
        const int r = (wc << 6) + (n << 4) + l15;
        const int off = ((ks << 6) + (lh << 4)) ^ ((r & 7) << 4);
        bfr[n] = *(const short8*)((const char*)Bs + r * 128 + off);
      }
      __builtin_amdgcn_s_setprio(1);
#pragma unroll
      for (int m = 0; m < 4; ++m)
#pragma unroll
        for (int n = 0; n < 4; ++n)
          acc[m][n] = __builtin_amdgcn_mfma_f32_16x16x32_bf16(af[m], bfr[n], acc[m][n], 0, 0, 0);
      __builtin_amdgcn_s_setprio(0);
    }
    __syncthreads();
  }

  const int cseg = colTile / 9;            // 0=Q 1=K 2=V (block-uniform)
  const int cwithin = (colTile % 9) << 7;  // col base within segment
  if (cseg < 2) {
    short* dst = (cseg == 0) ? Qb : Kp;
    const float* bias = (cseg == 0) ? bq : bk;
    const float scl = (cseg == 0) ? QSCALE_L2E : 1.0f;
    const int rstride = (cseg == 0) ? 72 : KSTRIDE;
#pragma unroll
    for (int n = 0; n < 4; ++n) {
      const int c = cwithin + (wc << 6) + (n << 4) + l15;
      const int h = c / 72;
      const int d = c - h * 72;
      const float bvx = bias[c];
#pragma unroll
      for (int m = 0; m < 4; ++m)
#pragma unroll
        for (int i = 0; i < 4; ++i) {
          const int r = row0 + (wr << 6) + (m << 4) + (lh << 2) + i;
          const int b = r >> 10, s = r & 1023;
          dst[(size_t)((((b << 4) + h) << 10) + s) * rstride + d] =
              f2bf((acc[m][n][i] + bvx) * scl);
        }
    }
  } else {
    // ---- V segment: LDS transpose -> coalesced [d][s] stores ----
    const int b = row0 >> 10;
    const int sb = row0 & 1023;
    short* Td = SM;  // 64 cols x 264 (rows 0..255 + pad)
#pragma unroll
    for (int p = 0; p < 2; ++p) {
      if (wc == p) {
#pragma unroll
        for (int n = 0; n < 4; ++n) {
          const int ci = n * 16 + l15;  // 0..63 within pass
          const float bvx = bv[cwithin + p * 64 + ci];
#pragma unroll
          for (int m = 0; m < 4; ++m) {
            const int r0 = (wr << 6) + (m << 4) + (lh << 2);
            short4 o;
            o.x = f2bf(acc[m][n][0] + bvx);
            o.y = f2bf(acc[m][n][1] + bvx);
            o.z = f2bf(acc[m][n][2] + bvx);
            o.w = f2bf(acc[m][n][3] + bvx);
            *(short4*)(Td + ci * 264 + r0) = o;
          }
        }
      }
      __syncthreads();
      {
        const int ci = tid >> 3;    // 0..63
        const int part = tid & 7;   // 0..7, 32 shorts each
        const int cg = cwithin + p * 64 + ci;
        const int h = cg / 72;
        const int d = cg - h * 72;
        short* dstp = Vt + (((size_t)(((b << 4) + h) * 80 + d)) << 10) + sb + part * 32;
        const short* srcp = Td + ci * 264 + part * 32;
#pragma unroll
        for (int k = 0; k < 4; ++k)
          *(short8*)(dstp + k * 8) = *(const short8*)(srcp + k * 8);
      }
      __syncthreads();
    }
  }
}

// ---------------- O GEMM: 256x128 tile, 512 threads, fp32 out ---------------
__global__ __launch_bounds__(512) void k_gemm_o(const short* __restrict__ A,
                                                const short* __restrict__ Bt,
                                                const float* __restrict__ bias,
                                                float* __restrict__ C) {
  __shared__ __align__(16) short SM[24576];
  short* As = SM;          // [256][64]
  short* Bs = SM + 16384;  // [128][64]
  const int tid = threadIdx.x;
  const int lane = tid & 63;
  const int wid = tid >> 6;
  const int wr = wid >> 1, wc = wid & 1;
  // XCD-chunked bijective swizzle over 288 blocks (288 = 8*36)
  const int flat = blockIdx.y * 9 + blockIdx.x;
  const int rid = (flat & 7) * 36 + (flat >> 3);
  const int row0 = (rid / 9) << 8;
  const int col0 = (rid % 9) << 7;
  const int l15 = lane & 15, lh = lane >> 4;
  const int lr8 = lane >> 3;
  const int csrc = ((lane & 7) ^ lr8) << 3;

  const f32x4 fz = {0.f, 0.f, 0.f, 0.f};
  f32x4 acc[4][4];
#pragma unroll
  for (int m = 0; m < 4; ++m)
#pragma unroll
    for (int n = 0; n < 4; ++n) acc[m][n] = fz;

  for (int k0 = 0; k0 < HIDDEN; k0 += 64) {
#pragma unroll
    for (int i = 0; i < 4; ++i) {  // A: 32 chunks of 1KB
      const int c = (wid << 2) + i;
      const int r = (c << 3) + lr8;
      gload16(A + (size_t)(row0 + r) * HIDDEN + k0 + csrc, (void*)(As + (c << 9)));
    }
#pragma unroll
    for (int i = 0; i < 2; ++i) {  // B: 16 chunks of 1KB
      const int c = (wid << 1) + i;
      const int r = (c << 3) + lr8;
      gload16(Bt + (size_t)(col0 + r) * HIDDEN + k0 + csrc, (void*)(Bs + (c << 9)));
    }
    __syncthreads();
#pragma unroll
    for (int ks = 0; ks < 2; ++ks) {
      short8 af[4], bfr[4];
#pragma unroll
      for (int m = 0; m < 4; ++m) {
        const int r = (wr << 6) + (m << 4) + l15;
        const int off = ((ks << 6) + (lh << 4)) ^ ((r & 7) << 4);
        af[m] = *(const short8*)((const char*)As + r * 128 + off);
      }
#pragma unroll
      for (int n = 0; n < 4; ++n) {
        const int r = (wc << 6) + (n << 4) + l15;
        const int off = ((ks << 6) + (lh << 4)) ^ ((r & 7) << 4);
        bfr[n] = *(const short8*)((const char*)Bs + r * 128 + off);
      }
      __builtin_amdgcn_s_setprio(1);
#pragma unroll
      for (int m = 0; m < 4; ++m)
#pragma unroll
        for (int n = 0; n < 4; ++n)
          acc[m][n] = __builtin_amdgcn_mfma_f32_16x16x32_bf16(af[m], bfr[n], acc[m][n], 0, 0, 0);
      __builtin_amdgcn_s_setprio(0);
    }
    __syncthreads();
  }

#pragma unroll
  for (int n = 0; n < 4; ++n) {
    const int c = col0 + (wc << 6) + (n << 4) + l15;
    const float bvx = bias[c];
#pragma unroll
    for (int m = 0; m < 4; ++m)
#pragma unroll
      for (int i = 0; i < 4; ++i) {
        const int r = row0 + (wr << 6) + (m << 4) + (lh << 2) + i;
        C[(size_t)r * HIDDEN + c] = acc[m][n][i] + bvx;
      }
  }
}

// ------- Flash attention: fixed-max softmax (shift folded into GEMM), -------
// 8 waves x 32 q-rows = 256 q-rows/block. grid 512 (XCD-chunked). KB=64.
__global__ __launch_bounds__(512, 4) void k_attn(const short* __restrict__ Qg,
                                                 const short* __restrict__ Kp,
                                                 const short* __restrict__ Vt,
                                                 short* __restrict__ Og) {
  __shared__ __align__(16) short Ks[64 * KSTRIDE];  // 13312 B, linear
  __shared__ __align__(16) short Vs[80 * 64];       // 10240 B, XOR-swizzled content
  __shared__ __align__(16) short Ps[8 * 16 * 72];   // 18432 B, per-wave 16 q-rows
  const int tid = threadIdx.x, lane = tid & 63, wid = tid >> 6;  // wid 0..7
  const int l15 = lane & 15, lh = lane >> 4;
  const int id = blockIdx.x;
  const int rid = (id & 7) * 64 + (id >> 3);  // 512 blocks, XCD-chunked
  const int bh = rid >> 2;
  const int q0 = (rid & 3) << 8;  // 256 q-rows per block
  const short8 sz = {0, 0, 0, 0, 0, 0, 0, 0};
  const f32x4 fz = {0.f, 0.f, 0.f, 0.f};

  // Q fragments (pre-scaled by log2e/sqrt(72)); k-slot 72 = 1.0 pairs with
  // K col 72 = -8.0 to shift every score by -8 (fixed-max softmax).
  short8 qf[2][3];
#pragma unroll
  for (int m = 0; m < 2; ++m)
#pragma unroll
    for (int ks = 0; ks < 3; ++ks) {
      const int row = q0 + wid * 32 + m * 16 + l15;
      const int e0 = ks * 32 + lh * 8;
      if (e0 < 72)
        qf[m][ks] = *(const short8*)(Qg + ((size_t)bh * 1024 + row) * 72 + e0);
      else if (e0 == 72) {
        short8 v = sz;
        v[0] = (short)0x3F80;  // k=72 -> 1.0
        qf[m][ks] = v;
      } else
        qf[m][ks] = sz;
    }

  f32x4 oacc[2][5];  // oacc[m][4] col d=72 accumulates the softmax denominator
#pragma unroll
  for (int m = 0; m < 2; ++m)
#pragma unroll
    for (int no = 0; no < 5; ++no) oacc[m][no] = fz;

  const char* kgb = (const char*)Kp + ((size_t)bh * 1024) * (KSTRIDE * 2);
  const char* vgb = (const char*)Vt + (size_t)bh * 163840;
  short* psw = Ps + wid * 1152;

  for (int kt = 0; kt < 16; ++kt) {
    // ---- stage K tile: 13 contiguous 1KB chunks over 8 waves ----
    const char* kg = kgb + (size_t)kt * 64 * (KSTRIDE * 2);
    for (int c = wid; c < 13; c += 8)
      gload16(kg + c * 1024 + lane * 16, (char*)Ks + c * 1024);
    // ---- stage V tile: linear LDS, pre-swizzled global source ----
    for (int c = wid; c < 10; c += 8) {
      const int p = c * 1024 + lane * 16;
      const int d = p >> 7;                       // 0..79
      const int sc16 = (lane & 7) ^ (d & 7);      // swizzled source chunk
      gload16(vgb + (size_t)d * 2048 + kt * 128 + sc16 * 16, (char*)Vs + c * 1024);
    }
    __syncthreads();

#pragma unroll
    for (int m = 0; m < 2; ++m) {
      // ---- QK^T swapped: lane holds 16 consecutive keys of q-row l15 ----
      f32x4 sa[4];
#pragma unroll
      for (int n = 0; n < 4; ++n) sa[n] = fz;
#pragma unroll
      for (int ks = 0; ks < 3; ++ks) {
        short8 kf[4];
#pragma unroll
        for (int n = 0; n < 4; ++n)
          kf[n] = *(const short8*)((const char*)Ks + (n * 16 + l15) * 208 + ks * 64 + lh * 16);
        __builtin_amdgcn_s_setprio(1);
#pragma unroll
        for (int n = 0; n < 4; ++n)
          sa[n] = __builtin_amdgcn_mfma_f32_16x16x32_bf16(kf[n], qf[m][ks], sa[n], 0, 0, 0);
        __builtin_amdgcn_s_setprio(0);
      }

      // ---- fixed-max softmax: P = exp2(score - 8), shift already in score --
#pragma unroll
      for (int n = 0; n < 4; ++n)
#pragma unroll
        for (int i = 0; i < 4; ++i) sa[n][i] = fexp2(sa[n][i]);

      // ---- P -> per-wave LDS (bf16 pack via v_perm, ds_write_b64) ----
#pragma unroll
      for (int n = 0; n < 4; ++n) {
        unsigned w0 = __builtin_amdgcn_perm(__float_as_uint(sa[n][1]),
                                            __float_as_uint(sa[n][0]), 0x07060302u);
        unsigned w1 = __builtin_amdgcn_perm(__float_as_uint(sa[n][3]),
                                            __float_as_uint(sa[n][2]), 0x07060302u);
        uint2 w = {w0, w1};
        *(uint2*)((char*)psw + l15 * 144 + n * 32 + lh * 8) = w;
      }

      // ---- PV (ones-column at d=72 -> denominator in oacc[m][4]) ----
#pragma unroll
      for (int ks = 0; ks < 2; ++ks) {
        const short8 pa = *(const short8*)((const char*)psw + l15 * 144 + ks * 64 + lh * 16);
        short8 vb[5];
        const int cc = ((ks << 2) + lh) ^ (l15 & 7);
#pragma unroll
        for (int no = 0; no < 5; ++no)
          vb[no] = *(const short8*)((const char*)Vs + no * 2048 + l15 * 128 + cc * 16);
        __builtin_amdgcn_s_setprio(1);
#pragma unroll
        for (int no = 0; no < 5; ++no)
          oacc[m][no] = __builtin_amdgcn_mfma_f32_16x16x32_bf16(pa, vb[no], oacc[m][no], 0, 0, 0);
        __builtin_amdgcn_s_setprio(0);
      }
    }
    __syncthreads();
  }

  // ---- epilogue: denominator for rows lh*4+i lives at lane (l15=8, same lh)
  const int b = bh >> 4, h = bh & 15;
#pragma unroll
  for (int m = 0; m < 2; ++m) {
    float inv[4];
#pragma unroll
    for (int i = 0; i < 4; ++i)
      inv[i] = 1.0f / __shfl(oacc[m][4][i], (lane & 48) + 8);
#pragma unroll
    for (int no = 0; no < 5; ++no) {
      const int d = no * 16 + l15;
      if (d < 72) {
#pragma unroll
        for (int i = 0; i < 4; ++i) {
          const int s = q0 + wid * 32 + m * 16 + lh * 4 + i;
          Og[((size_t)(b * 1024 + s)) * HIDDEN + h * 72 + d] = f2bf(oacc[m][no][i] * inv[i]);
        }
      }
    }
  }
}

// ---------------- launch ----------------
extern "C" void kernel_launch(void* const* d_in, const int* in_sizes, int n_in,
                              void* d_out, int out_size, void* d_ws, size_t ws_size,
                              hipStream_t stream) {
  const float* x  = (const float*)d_in[0];
  const float* wq = (const float*)d_in[1];
  const float* bq = (const float*)d_in[2];
  const float* wk = (const float*)d_in[3];
  const float* bk = (const float*)d_in[4];
  const float* wv = (const float*)d_in[5];
  const float* bv = (const float*)d_in[6];
  const float* wo = (const float*)d_in[7];
  const float* bo = (const float*)d_in[8];

  char* ws = (char*)d_ws;
  short* xb = (short*)ws;                    // 18,874,368 B (bf16 x; reused as attn out)
  short* wT = (short*)(ws + 18874368);       // 10,616,832 B
  short* Qb = (short*)(ws + 29491200);       // 18,874,368 B [bh][s][72]
  short* Kp = (short*)(ws + 48365568);       // 27,262,976 B [bh][s][104] padded
  short* Vt = (short*)(ws + 75628544);       // 20,971,520 B [bh][80][1024]
  const size_t WSZ = (size_t)HIDDEN * HIDDEN;

  k_prep<<<5632, 256, 0, stream>>>(x, xb, Kp, Vt);
  k_cvtw<<<dim3(18, 18, 4), 256, 0, stream>>>(wq, wk, wv, wo, wT);

  k_gemm_qkv<<<dim3(27, 32), 512, 0, stream>>>(xb, wT, bq, bk, bv, Qb, Kp, Vt);
  k_attn<<<512, 512, 0, stream>>>(Qb, Kp, Vt, xb);
  k_gemm_o<<<dim3(9, 32), 512, 0, stream>>>(xb, wT + 3 * WSZ, bo, (float*)d_out);
}